// Round 7
// baseline (1738.660 us; speedup 1.0000x reference)
//
#include <hip/hip_runtime.h>
#include <cstdint>

#define Bn 4
#define Nn 16384
#define Mn 512
#define Kn 32

// output offsets (floats)
#define O_SAL 6144
#define O_RC  8192
#define O_AFM 794624

__device__ __forceinline__ unsigned fkey(float f) {
  unsigned b = __float_as_uint(f);
  return (b & 0x80000000u) ? ~b : (b | 0x80000000u);
}

__device__ __forceinline__ unsigned long long dkey(double d) {
  unsigned long long b = (unsigned long long)__double_as_longlong(d);
  return (b & 0x8000000000000000ull) ? ~b : (b | 0x8000000000000000ull);
}

// ---- kernel 0: per-point squared norm (np: materialized square + seq sum, NO FMA) ----
// Also zeroes the 32 fps sync slots (runs before fps on the same stream;
// kernel boundary guarantees visibility).
__global__ __launch_bounds__(256) void sq_kernel(const float* __restrict__ x,
                                                 float* __restrict__ sqp,
                                                 unsigned long long* __restrict__ slots) {
#pragma clang fp contract(off)
  int i = blockIdx.x * 256 + threadIdx.x;  // < B*N
  if (blockIdx.x == 0 && threadIdx.x < 32) slots[threadIdx.x * 8] = 0ull;
  float4 v = ((const float4*)x)[i];
  float qx = v.x * v.x;
  float qy = v.y * v.y;
  float qz = v.z * v.z;
  sqp[i] = (qx + qy) + qz;
}

// DPP max step: moved = lane-shuffled v (old = self fallback), then max.
// Values are >= 0 here, so either bound_ctrl semantic (old or 0) is safe.
template <int CTRL>
__device__ __forceinline__ float dppmaxf(float v) {
  int m = __builtin_amdgcn_update_dpp(__float_as_int(v), __float_as_int(v),
                                      CTRL, 0xf, 0xf, false);
  return fmaxf(v, __int_as_float(m));
}

// ---------------- kernel 1: farthest point sampling (fp32, NO contraction) ----------------
// r2-r5 lesson: the allocator pins a ~64-reg budget for this kernel no matter
// what attributes we use (VGPR=52/SGPR=112 across 4 structurally different
// versions) and spills the 64-float resident state to scratch - the 2x VALU
// inflation that made every op-count reduction a no-op. So: SHRINK THE STATE.
// 4 blocks per batch (16 blocks total, all co-resident), 4 pts/thread ->
// 16 resident VGPRs; fits any budget, no spills, and 4x less VALU per step.
// Cross-block sync per step: one u64 per (parity, batch, block), ALIASED INTO
// THE gcf WORKSPACE REGION (r6 container crash was most plausibly the extra
// 2KB appended past the 2,654,208-byte workspace footprint -> OOB atomics;
// gcf is only written by group_kernel which runs after fps, and sq_kernel
// zeroes the slots before fps, so aliasing is race-free and adds 0 bytes).
// Slot value = [tag:s (18b) | fkey:32 | (16383-idx):14]. Tag inside the word
// => single relaxed agent-scope atomic store/load, no fences. Parity
// double-buffer: slot for step s only rewritten at s+2, which the writer can
// reach only after all blocks posted s+1, which requires every reader to have
// finished s -> race-free. rocprof re-runs without re-zero are benign: the
// kernel is deterministic, so any stale tag==s value equals the fresh one.
// Ties: per-block lowest idx, cross-block max of (fkey, 16383-idx) == global
// lowest tying idx == flat-scan semantics. Distance math unchanged:
// contract(off), (qx+qy)+qz, fminf, exact-equality lowest-index.
__global__ __launch_bounds__(1024)
void fps_kernel(const float* __restrict__ x, float* __restrict__ node,
                unsigned long long* __restrict__ slots) {
#pragma clang fp contract(off)
  const int gb = blockIdx.x;
  const int bb = gb >> 2;   // batch
  const int blk = gb & 3;   // sub-block within batch
  const int t = threadIdx.x;
  const float4* xb = (const float4*)(x + (size_t)bb * Nn * 4);
  float px[4], py[4], pz[4], mind[4];
  const int base = blk * 4096 + t * 4;
#pragma unroll
  for (int i = 0; i < 4; ++i) {
    float4 v = xb[base + i];
    px[i] = v.x; py[i] = v.y; pz[i] = v.z;
    mind[i] = 1e10f;
  }
  __shared__ __align__(16) unsigned long long kkey[16];
  __shared__ unsigned long long rslot[4];
  float cx, cy, cz;
  {
    float4 v = xb[0];
    cx = v.x; cy = v.y; cz = v.z;
    if (blk == 0 && t == 0) ((float4*)node)[bb * Mn] = v;
  }
  for (int s = 1; s < Mn; ++s) {
    // pass 1: distance + running min (exact np order, no contraction)
#pragma unroll
    for (int i = 0; i < 4; ++i) {
      float dx = px[i] - cx;
      float dy = py[i] - cy;
      float dz = pz[i] - cz;
      float qx = dx * dx;
      float qy = dy * dy;
      float qz = dz * dz;
      float d = (qx + qy) + qz;
      mind[i] = fminf(mind[i], d);
    }
    // pass 2: value max; pass 3: lowest matching local index
    float bv = fmaxf(fmaxf(mind[0], mind[1]), fmaxf(mind[2], mind[3]));
    int isel = 0;
#pragma unroll
    for (int i = 3; i >= 0; --i)
      if (mind[i] == bv) isel = i;
    // wave reduce: value-only DPP max -> lane 63 -> ballot lowest tying lane
    float r = bv;
    r = dppmaxf<0x111>(r);  // row_shr:1
    r = dppmaxf<0x112>(r);  // row_shr:2
    r = dppmaxf<0x114>(r);  // row_shr:4
    r = dppmaxf<0x118>(r);  // row_shr:8
    r = dppmaxf<0x142>(r);  // row_bcast:15
    r = dppmaxf<0x143>(r);  // row_bcast:31
    float wmax = __int_as_float(__builtin_amdgcn_readlane(__float_as_int(r), 63));
    unsigned long long ball = __ballot(bv == wmax);
    int wl = __ffsll(ball) - 1;            // lowest tying lane
    int widx = __builtin_amdgcn_readlane(base + isel, wl);
    if ((t & 63) == 0) {
      kkey[t >> 6] =
          ((unsigned long long)(__float_as_uint(wmax) | 0x80000000u) << 32) |
          (unsigned)(~widx);
    }
    __syncthreads();
    if (t < 64) {
      // wave 0: combine 16 wave keys; lane 0 posts the block winner; lanes
      // 0-3 spin-read the 4 block slots of this batch into LDS.
      unsigned long long kk = kkey[t & 15];
#pragma unroll
      for (int off = 1; off < 16; off <<= 1) {
        unsigned long long ok = __shfl_xor(kk, off, 16);
        kk = ok > kk ? ok : kk;
      }
      if (t == 0) {
        unsigned bidx = ~(unsigned)(kk & 0xFFFFFFFFu);
        unsigned long long v46 = ((kk >> 32) << 14) |
                                 (unsigned long long)(unsigned)(16383 - (int)bidx);
        unsigned long long word = ((unsigned long long)s << 46) | v46;
        __hip_atomic_store(&slots[((s & 1) * 16 + bb * 4 + blk) * 8], word,
                           __ATOMIC_RELAXED, __HIP_MEMORY_SCOPE_AGENT);
      }
      if (t < 4) {
        unsigned long long vv;
        do {
          vv = __hip_atomic_load(&slots[((s & 1) * 16 + bb * 4 + t) * 8],
                                 __ATOMIC_RELAXED, __HIP_MEMORY_SCOPE_AGENT);
          if ((vv >> 46) != (unsigned long long)s) __builtin_amdgcn_s_sleep(1);
        } while ((vv >> 46) != (unsigned long long)s);
        rslot[t] = vv & ((1ull << 46) - 1);
      }
    }
    __syncthreads();
    {
      unsigned long long v0 = rslot[0], v1 = rslot[1];
      unsigned long long v2 = rslot[2], v3 = rslot[3];
      unsigned long long va = v0 > v1 ? v0 : v1;
      unsigned long long vb = v2 > v3 ? v2 : v3;
      unsigned long long vm = va > vb ? va : vb;
      int wi = 16383 - (int)(vm & 16383u);
      wi = __builtin_amdgcn_readfirstlane(wi);
      float4 nv = xb[wi];
      cx = nv.x; cy = nv.y; cz = nv.z;
      if (blk == 0 && t == 0) ((float4*)node)[bb * Mn + s] = nv;
    }
  }
}

// ------- kernel 2: top-64 kNN. sq terms NON-FMA (np materialized square);
// dot = BLAS/XLA sequential forward FMA: fma(z,z', fma(y,y', x*x'));
// combine (sqm+sqp) - 2*dot unfused. Stable lowest-index ties.
// Radix select BYTE-wise: 4 passes x 256 bins - same counts, same rank
// semantics, same threshold; half the scan work, fewer barriers, atomic
// contention spread over 256 addresses. -------
__global__ __launch_bounds__(256) void knn_kernel(const float* __restrict__ x,
                                                  const float* __restrict__ node,
                                                  const float* __restrict__ sqp,
                                                  const int* __restrict__ rand_idx,
                                                  int* __restrict__ sel) {
#pragma clang fp contract(off)
  const int bm = blockIdx.x;
  const int b = bm >> 9;
  const int t = threadIdx.x;
  const float4* xb = (const float4*)(x + (size_t)b * Nn * 4);
  const float* sq_b = sqp + b * Nn;
  float4 nd = ((const float4*)node)[bm];
  const float nx = nd.x, ny = nd.y, nz = nd.z;
  // node's own sq, same non-FMA form as sq_kernel (np reads it from the
  // same materialized array)
  const float sqmf = (nx * nx + ny * ny) + nz * nz;
  unsigned key[64];
#pragma unroll
  for (int i = 0; i < 64; ++i) {
    int n = t + (i << 8);
    float4 v = xb[n];
    // GEMM microkernel accumulation: acc = x*x' (rounded), acc = fma(y,y',acc),
    // acc = fma(z,z',acc)  — explicit fmaf, immune to contract(off)
    float dot = nx * v.x;
    dot = __builtin_fmaf(ny, v.y, dot);
    dot = __builtin_fmaf(nz, v.z, dot);
    float d2 = (sqmf + sq_b[n]) - 2.0f * dot;
    key[i] = fkey(d2);
  }
  // radix-select the rank-95 (0-indexed) key -> guard-banded superset
  __shared__ unsigned hist[256];
  __shared__ unsigned gsum[16];
  __shared__ unsigned sh_prefix;
  __shared__ int sh_r;
  unsigned prefix = 0, pmask = 0;
  int r = 95;
  for (int shift = 24; shift >= 0; shift -= 8) {
    hist[t] = 0;
    __syncthreads();
#pragma unroll
    for (int i = 0; i < 64; ++i) {
      if ((key[i] & pmask) == prefix) atomicAdd(&hist[(key[i] >> shift) & 255], 1u);
    }
    __syncthreads();
    if (t < 16) {
      unsigned ssum = 0;
#pragma unroll
      for (int j = 0; j < 16; ++j) ssum += hist[t * 16 + j];
      gsum[t] = ssum;
    }
    __syncthreads();
    if (t == 0) {
      int rr = r;
      unsigned g = 0;
      for (unsigned j = 0; j < 16; ++j) {
        int c = (int)gsum[j];
        if (rr < c) { g = j; break; }
        rr -= c;
      }
      unsigned bin = g * 16;
      for (unsigned j = 0; j < 16; ++j) {
        int c = (int)hist[g * 16 + j];
        if (rr < c) { bin = g * 16 + j; break; }
        rr -= c;
      }
      sh_prefix = prefix | (bin << shift);
      sh_r = rr;
    }
    __syncthreads();
    prefix = sh_prefix;
    r = sh_r;
    pmask |= (0xFFu << shift);
  }
  const unsigned T = prefix;  // collect all keys <= T (>=96 candidates; cap 128)
  __shared__ int cnt;
  __shared__ unsigned long long karr[128];
  if (t == 0) cnt = 0;
  __syncthreads();
#pragma unroll
  for (int i = 0; i < 64; ++i) {
    if (key[i] <= T) {
      int pos = atomicAdd(&cnt, 1);
      if (pos < 128) {
        unsigned n = (unsigned)(t + (i << 8));
        // idx in low bits: ascending sort => equal d2 resolved LOWEST index first
        karr[pos] = ((unsigned long long)key[i] << 32) | n;
      }
    }
  }
  __syncthreads();
  const int nc = cnt < 128 ? cnt : 128;
  if (t < 128 && t >= nc) karr[t] = ~0ull;
  // 128-wide bitonic sort ascending
  for (int k = 2; k <= 128; k <<= 1) {
    for (int j = k >> 1; j > 0; j >>= 1) {
      __syncthreads();
      if (t < 64) {
        int i = ((t & ~(j - 1)) << 1) | (t & (j - 1));
        int ip = i | j;
        unsigned long long ka = karr[i], kb = karr[ip];
        bool asc = ((i & k) == 0);
        if ((ka > kb) == asc) { karr[i] = kb; karr[ip] = ka; }
      }
    }
  }
  __syncthreads();
  if (t < 32) {
    int ri = rand_idx[t];  // in [0,64)
    sel[bm * 32 + t] = (int)(unsigned)(karr[ri] & 0xFFFFFFFFu);
  }
}

// ---- top-8 over 32 candidates, lowest-idx ties (fp64 keys) ----
__device__ __forceinline__ void topk8(const unsigned long long* row, unsigned char* nb) {
  unsigned long long bk[8];
  unsigned char bi[8];
#pragma unroll
  for (int k = 0; k < 8; ++k) { bk[k] = ~0ull; bi[k] = 255; }
  for (int q = 0; q < 32; ++q) {
    unsigned long long kv = row[q];
    if (kv < bk[7]) {
      bk[7] = kv; bi[7] = (unsigned char)q;
#pragma unroll
      for (int k = 6; k >= 0; --k) {
        if (bk[k + 1] < bk[k]) {
          unsigned long long tk = bk[k]; bk[k] = bk[k + 1]; bk[k + 1] = tk;
          unsigned char ti = bi[k]; bi[k] = bi[k + 1]; bi[k + 1] = ti;
        }
      }
    }
  }
#pragma unroll
  for (int k = 0; k < 8; ++k) nb[k] = bi[k];
}

// ---------------- kernel 3: fused group pipeline ----------------
__global__ __launch_bounds__(256) void group_kernel(
    const float* __restrict__ x, const float* __restrict__ node,
    const int* __restrict__ sel, const float* __restrict__ w_e1,
    const float* __restrict__ g1, const float* __restrict__ b1,
    const float* __restrict__ w_e2, const float* __restrict__ g2,
    const float* __restrict__ b2, float* __restrict__ out,
    float* __restrict__ gcf) {
#pragma clang fp contract(off)
  const int bm = blockIdx.x;
  const int b = bm >> 9;
  const int m = bm & 511;
  const int t = threadIdx.x;

  __shared__ float cl[32][13];
  __shared__ float h1t[64][36];
  __shared__ float h1p[32][68];
  __shared__ unsigned char nbr[32][8];
  __shared__ double sqs[32];
  __shared__ float part[4][32];
  __shared__ float aws[32];
  __shared__ union U {
    struct {
      unsigned long long keys[32][32];
      float we_a[12][64];
      float we_d[12][64];
      float a1[32][65];
      float cd1[32][65];
    } s;
    float a2[32 * 256];
  } u;

  const float4* xb = (const float4*)(x + (size_t)b * Nn * 4);
  const float4 ndv = ((const float4*)node)[bm];

  if (t < 32) {
    int n = sel[bm * 32 + t];
    float4 v = xb[n];
    float rx = v.x - ndv.x;
    float ry = v.y - ndv.y;
    float rz = v.z - ndv.z;
    float ds = (rx * rx + ry * ry) + rz * rz;
    ds = __fsqrt_rn(ds);
    cl[t][0] = ndv.x; cl[t][1] = ndv.y; cl[t][2] = ndv.z; cl[t][3] = ndv.w;
    cl[t][4] = v.x;   cl[t][5] = v.y;   cl[t][6] = v.z;   cl[t][7] = v.w;
    cl[t][8] = rx;    cl[t][9] = ry;    cl[t][10] = rz;   cl[t][11] = ds;
  }
  for (int i = t; i < 768; i += 256) {
    int row = i >> 6, d = i & 63;
    float wa = w_e1[row * 64 + d];
    float wb = w_e1[(row + 12) * 64 + d];
    u.s.we_a[row][d] = wa;
    u.s.we_d[row][d] = wb - wa;
  }
  __syncthreads();

  for (int i = t; i < 384; i += 256) {
    int c = i >> 5, p = i & 31;
    out[O_RC + (((size_t)(b * 12 + c) * 512) + m) * 32 + p] = cl[p][c];
  }
  if (t < 32) {
    double q[12];
#pragma unroll
    for (int c = 0; c < 12; ++c) {
      double cv = (double)cl[t][c];
      q[c] = cv * cv;
    }
    double s01 = q[0] + q[1];
    double s23 = q[2] + q[3];
    double s45 = q[4] + q[5];
    double s67 = q[6] + q[7];
    double s = (s01 + s23) + (s45 + s67);
    s = s + q[8];
    s = s + q[9];
    s = s + q[10];
    s = s + q[11];
    sqs[t] = s;
  }
  __syncthreads();

  // pairwise d2 (12-d, fp64 order-exact) -> keys
  {
    int p = t >> 3, q0 = (t & 7) << 2;
#pragma unroll
    for (int qq = 0; qq < 4; ++qq) {
      int q = q0 + qq;
      double dot = 0.0;
#pragma unroll
      for (int c = 0; c < 12; ++c)
        dot = dot + (double)cl[p][c] * (double)cl[q][c];
      double d2 = (sqs[p] + sqs[q]) - 2.0 * dot;
      u.s.keys[p][q] = dkey(d2);
    }
  }
  __syncthreads();

  if (t < 32) topk8(&u.s.keys[t][0], &nbr[t][0]);
  {
    int d = t & 63, pg = (t >> 6) << 3;
#pragma unroll
    for (int pp = 0; pp < 8; ++pp) {
      int p = pg + pp;
      float aA = 0.f, aD = 0.f;
#pragma unroll
      for (int c = 0; c < 12; ++c) {
        float xv = cl[p][c];
        aA = fmaf(xv, u.s.we_a[c][d], aA);
        aD = fmaf(xv, u.s.we_d[c][d], aD);
      }
      u.s.a1[p][d] = aA;
      u.s.cd1[p][d] = aD;
    }
  }
  __syncthreads();

  {
    int d = t & 63, pg = (t >> 6) << 3;
    float g1v = g1[d], b1v = b1[d];
#pragma unroll
    for (int pp = 0; pp < 8; ++pp) {
      int p = pg + pp;
      float cd = u.s.cd1[p][d];
      float hm = -1e30f;
#pragma unroll
      for (int k = 0; k < 8; ++k) {
        int j = nbr[p][k];
        float hv = fmaf(g1v, u.s.a1[j][d] + cd, b1v);
        hv = fmaxf(hv, 0.f);
        hm = fmaxf(hm, hv);
      }
      h1t[d][p] = hm;
      h1p[p][d] = hm;
    }
  }
  __syncthreads();

  if (t < 32) {
    double r[8];
#pragma unroll
    for (int j = 0; j < 8; ++j) {
      double hv = (double)h1p[t][j];
      r[j] = hv * hv;
    }
#pragma unroll
    for (int blk = 1; blk < 8; ++blk) {
#pragma unroll
      for (int j = 0; j < 8; ++j) {
        double hv = (double)h1p[t][blk * 8 + j];
        r[j] = r[j] + hv * hv;
      }
    }
    double s01 = r[0] + r[1];
    double s23 = r[2] + r[3];
    double s45 = r[4] + r[5];
    double s67 = r[6] + r[7];
    sqs[t] = (s01 + s23) + (s45 + s67);
  }
  __syncthreads();

  {
    int p = t >> 3, q0 = (t & 7) << 2;
#pragma unroll
    for (int qq = 0; qq < 4; ++qq) {
      int q = q0 + qq;
      double dot = 0.0;
      for (int c = 0; c < 64; ++c)
        dot = dot + (double)h1p[p][c] * (double)h1p[q][c];
      double d2 = (sqs[p] + sqs[q]) - 2.0 * dot;
      u.s.keys[p][q] = dkey(d2);
    }
  }
  __syncthreads();

  if (t < 32) topk8(&u.s.keys[t][0], &nbr[t][0]);
  __syncthreads();

  float accD[32];
  float embv[32];
  {
    float accA[32];
#pragma unroll
    for (int p = 0; p < 32; ++p) { accA[p] = 0.f; accD[p] = 0.f; }
    for (int c = 0; c < 64; ++c) {
      float wt = w_e2[c * 256 + t];
      float wb = w_e2[(c + 64) * 256 + t];
      float wd = wb - wt;
      const float4* row = (const float4*)&h1t[c][0];
#pragma unroll
      for (int p4 = 0; p4 < 8; ++p4) {
        float4 hv = row[p4];
        accA[4 * p4 + 0] = fmaf(hv.x, wt, accA[4 * p4 + 0]);
        accA[4 * p4 + 1] = fmaf(hv.y, wt, accA[4 * p4 + 1]);
        accA[4 * p4 + 2] = fmaf(hv.z, wt, accA[4 * p4 + 2]);
        accA[4 * p4 + 3] = fmaf(hv.w, wt, accA[4 * p4 + 3]);
        accD[4 * p4 + 0] = fmaf(hv.x, wd, accD[4 * p4 + 0]);
        accD[4 * p4 + 1] = fmaf(hv.y, wd, accD[4 * p4 + 1]);
        accD[4 * p4 + 2] = fmaf(hv.z, wd, accD[4 * p4 + 2]);
        accD[4 * p4 + 3] = fmaf(hv.w, wd, accD[4 * p4 + 3]);
      }
    }
#pragma unroll
    for (int p = 0; p < 32; ++p) u.a2[p * 256 + t] = accA[p];
  }
  __syncthreads();
  {
    float g2v = g2[t], b2v = b2[t];
#pragma unroll
    for (int p = 0; p < 32; ++p) {
      float cd = accD[p];
      float e = -1e30f;
#pragma unroll
      for (int k = 0; k < 8; ++k) {
        int j = nbr[p][k];
        float hv = fmaf(g2v, u.a2[j * 256 + t] + cd, b2v);
        hv = fmaxf(hv, 0.f);
        e = fmaxf(e, hv);
      }
      embv[p] = e;
    }
  }

#pragma unroll
  for (int p = 0; p < 32; ++p) {
    float v = embv[p];
#pragma unroll
    for (int off = 32; off > 0; off >>= 1) v = fmaxf(v, __shfl_xor(v, off));
    if ((t & 63) == 0) part[t >> 6][p] = v;
  }
  __syncthreads();

  if (t < 32) {
    float x1 = fmaxf(fmaxf(part[0][t], part[1][t]), fmaxf(part[2][t], part[3][t]));
    float mx = x1;
#pragma unroll
    for (int off = 16; off > 0; off >>= 1) mx = fmaxf(mx, __shfl_xor(mx, off));
    float ex = expf(x1 - mx);
    float sm = ex;
#pragma unroll
    for (int off = 16; off > 0; off >>= 1) sm += __shfl_xor(sm, off);
    float aw = ex / sm;
    aws[t] = aw;
#pragma unroll
    for (int c = 0; c < 3; ++c) {
      float kv = aw * cl[t][4 + c];
#pragma unroll
      for (int off = 16; off > 0; off >>= 1) kv += __shfl_xor(kv, off);
      if (t == 0) out[((size_t)(b * 3 + c)) * 512 + m] = kv;
    }
  }
  __syncthreads();

  {
    float gsum = 0.f;
    size_t abase = (size_t)O_AFM + (((size_t)(b * 256 + t)) * 512 + m) * 32;
    float4* ap = (float4*)(out + abase);
#pragma unroll
    for (int p4 = 0; p4 < 8; ++p4) {
      float4 o;
      o.x = embv[4 * p4 + 0] * aws[4 * p4 + 0];
      o.y = embv[4 * p4 + 1] * aws[4 * p4 + 1];
      o.z = embv[4 * p4 + 2] * aws[4 * p4 + 2];
      o.w = embv[4 * p4 + 3] * aws[4 * p4 + 3];
      gsum += o.x; gsum += o.y; gsum += o.z; gsum += o.w;
      ap[p4] = o;
    }
    gcf[((size_t)(b * 256 + t)) * 512 + m] = gsum;
  }
}

// ---------------- kernel 4: MLP head ----------------
__global__ __launch_bounds__(256) void mlp_kernel(
    const float* __restrict__ gcf, const float* __restrict__ w_m1,
    const float* __restrict__ bm1, const float* __restrict__ gm1,
    const float* __restrict__ bbm1, const float* __restrict__ w_m2,
    const float* __restrict__ bm2, const float* __restrict__ gm2,
    const float* __restrict__ bbm2, const float* __restrict__ w_m3,
    const float* __restrict__ bm3, float* __restrict__ out) {
  const int blk = blockIdx.x;
  const int b = blk >> 4;
  const int m0 = (blk & 15) << 5;
  const int t = threadIdx.x;
  __shared__ float sbuf[256 * 36];

#pragma unroll
  for (int i = 0; i < 32; ++i) {
    int c = (t >> 5) + (i << 3);
    int j = t & 31;
    sbuf[c * 36 + j] = gcf[((size_t)(b * 256 + c)) * 512 + m0 + j];
  }
  __syncthreads();

  float acc[32];
#pragma unroll
  for (int j = 0; j < 32; ++j) acc[j] = 0.f;
  for (int c = 0; c < 256; ++c) {
    float wv = w_m1[c * 256 + t];
    const float4* row = (const float4*)&sbuf[c * 36];
#pragma unroll
    for (int j4 = 0; j4 < 8; ++j4) {
      float4 g4 = row[j4];
      acc[4 * j4 + 0] = fmaf(g4.x, wv, acc[4 * j4 + 0]);
      acc[4 * j4 + 1] = fmaf(g4.y, wv, acc[4 * j4 + 1]);
      acc[4 * j4 + 2] = fmaf(g4.z, wv, acc[4 * j4 + 2]);
      acc[4 * j4 + 3] = fmaf(g4.w, wv, acc[4 * j4 + 3]);
    }
  }
  float y[32];
  {
    float gv = gm1[t], bv = bm1[t], bbv = bbm1[t];
#pragma unroll
    for (int j = 0; j < 32; ++j) y[j] = fmaxf(fmaf(gv, acc[j] + bv, bbv), 0.f);
  }
  __syncthreads();
#pragma unroll
  for (int j = 0; j < 32; ++j) sbuf[t * 36 + j] = y[j];
  __syncthreads();

#pragma unroll
  for (int j = 0; j < 32; ++j) acc[j] = 0.f;
  for (int c = 0; c < 256; ++c) {
    float wv = w_m2[c * 256 + t];
    const float4* row = (const float4*)&sbuf[c * 36];
#pragma unroll
    for (int j4 = 0; j4 < 8; ++j4) {
      float4 g4 = row[j4];
      acc[4 * j4 + 0] = fmaf(g4.x, wv, acc[4 * j4 + 0]);
      acc[4 * j4 + 1] = fmaf(g4.y, wv, acc[4 * j4 + 1]);
      acc[4 * j4 + 2] = fmaf(g4.z, wv, acc[4 * j4 + 2]);
      acc[4 * j4 + 3] = fmaf(g4.w, wv, acc[4 * j4 + 3]);
    }
  }
  {
    float gv = gm2[t], bv = bm2[t], bbv = bbm2[t];
#pragma unroll
    for (int j = 0; j < 32; ++j) y[j] = fmaxf(fmaf(gv, acc[j] + bv, bbv), 0.f);
  }
  __syncthreads();
  {
    float w3v = w_m3[t];
#pragma unroll
    for (int j = 0; j < 32; ++j) sbuf[t * 36 + j] = y[j] * w3v;
  }
  __syncthreads();
  if (t < 32) {
    float s = 0.f;
    for (int d = 0; d < 256; ++d) s += sbuf[d * 36 + t];
    s += bm3[0];
    float sal = log1pf(expf(-fabsf(s))) + fmaxf(s, 0.f) + 0.001f;
    out[O_SAL + (size_t)b * 512 + m0 + t] = sal;
  }
}

extern "C" void kernel_launch(void* const* d_in, const int* in_sizes, int n_in,
                              void* d_out, int out_size, void* d_ws, size_t ws_size,
                              hipStream_t stream) {
  (void)in_sizes; (void)n_in; (void)out_size; (void)ws_size;
  const float* x = (const float*)d_in[0];
  const int* rand_idx = (const int*)d_in[1];
  const float* w_e1 = (const float*)d_in[2];
  const float* g1 = (const float*)d_in[3];
  const float* b1 = (const float*)d_in[4];
  const float* w_e2 = (const float*)d_in[5];
  const float* g2 = (const float*)d_in[6];
  const float* b2 = (const float*)d_in[7];
  const float* w_m1 = (const float*)d_in[8];
  const float* bm1 = (const float*)d_in[9];
  const float* gm1 = (const float*)d_in[10];
  const float* bbm1 = (const float*)d_in[11];
  const float* w_m2 = (const float*)d_in[12];
  const float* bm2 = (const float*)d_in[13];
  const float* gm2 = (const float*)d_in[14];
  const float* bbm2 = (const float*)d_in[15];
  const float* w_m3 = (const float*)d_in[16];
  const float* bm3 = (const float*)d_in[17];
  float* out = (float*)d_out;
  char* ws = (char*)d_ws;

  float* node = (float*)ws;                             // 32 KB
  float* sqp = (float*)(ws + 32768);                    // 256 KB
  int* sel = (int*)(ws + 32768 + 262144);               // 256 KB
  float* gcf = (float*)(ws + 32768 + 262144 + 262144);  // 2 MB
  // fps sync slots ALIAS the first 2 KB of the gcf region: gcf is only
  // written by group_kernel (after fps completes on this stream), and
  // sq_kernel zeroes the slots before fps. Zero extra workspace bytes used.
  unsigned long long* slots = (unsigned long long*)(ws + 32768 + 262144 + 262144);

  sq_kernel<<<256, 256, 0, stream>>>(x, sqp, slots);
  fps_kernel<<<4 * Bn, 1024, 0, stream>>>(x, node, slots);
  knn_kernel<<<Bn * Mn, 256, 0, stream>>>(x, node, sqp, rand_idx, sel);
  group_kernel<<<Bn * Mn, 256, 0, stream>>>(x, node, sel, w_e1, g1, b1, w_e2,
                                            g2, b2, out, gcf);
  mlp_kernel<<<64, 256, 0, stream>>>(gcf, w_m1, bm1, gm1, bbm1, w_m2, bm2, gm2,
                                     bbm2, w_m3, bm3, out);
}

// Round 8
// 1725.051 us; speedup vs baseline: 1.0079x; 1.0079x over previous
//
#include <hip/hip_runtime.h>
#include <cstdint>

#define Bn 4
#define Nn 16384
#define Mn 512
#define Kn 32

// output offsets (floats)
#define O_SAL 6144
#define O_RC  8192
#define O_AFM 794624

__device__ __forceinline__ unsigned fkey(float f) {
  unsigned b = __float_as_uint(f);
  return (b & 0x80000000u) ? ~b : (b | 0x80000000u);
}

__device__ __forceinline__ unsigned long long dkey(double d) {
  unsigned long long b = (unsigned long long)__double_as_longlong(d);
  return (b & 0x8000000000000000ull) ? ~b : (b | 0x8000000000000000ull);
}

// ---- kernel 0: per-point squared norm (np: materialized square + seq sum, NO FMA) ----
__global__ __launch_bounds__(256) void sq_kernel(const float* __restrict__ x,
                                                 float* __restrict__ sqp) {
#pragma clang fp contract(off)
  int i = blockIdx.x * 256 + threadIdx.x;  // < B*N
  float4 v = ((const float4*)x)[i];
  float qx = v.x * v.x;
  float qy = v.y * v.y;
  float qz = v.z * v.z;
  sqp[i] = (qx + qy) + qz;
}

// DPP max step: moved = lane-shuffled v (old = self fallback), then max.
// Values are >= 0 here, so either bound_ctrl semantic (old or 0) is safe.
template <int CTRL>
__device__ __forceinline__ float dppmaxf(float v) {
  int m = __builtin_amdgcn_update_dpp(__float_as_int(v), __float_as_int(v),
                                      CTRL, 0xf, 0xf, false);
  return fmaxf(v, __int_as_float(m));
}

// ---------------- kernel 1: farthest point sampling (fp32, NO contraction) ----------------
// 7-round synthesis: (r7) cross-block atomic sync costs ~1.3us/step (FETCH
// 526->2072KB, 70% of step = wait) -> multi-block is a dead end. (r2-r5) the
// allocator pins ~64 regs for a 1024-thread block and spills any 64-float
// resident state to scratch. (r7) small state => no spills (VGPR=20/SGPR=32).
// Therefore: ONE block per batch, small reg state, bulk data in LDS.
//   - px[16] + mind[16] in regs (32 resident VGPRs, fits any budget).
//   - y,z in 128KB dynamic LDS, TRANSPOSED: slot(i,t) = i*1024+t. Per-wave
//     ds_read_b64 hits bank 2*lane mod 32 -> 4 lanes/bank = minimum 4-cycle
//     service, no excess conflict. Layout is decoupled from index semantics.
//   - global index stays t*16+i (contiguous per thread): lowest tying lane +
//     lowest local i == lowest global index - tie semantics identical.
//   - one __syncthreads per step (kkey parity double-buffer), winner reload
//     via readfirstlane -> scalar load (uniform, L2).
// 128KB LDS also forces 1 block/CU -> 16 waves -> 4 waves/EU -> 128-reg
// budget via the occupancy path. Math unchanged: contract(off), (qx+qy)+qz,
// fminf chain, exact-equality lowest-index ties.
__global__ __launch_bounds__(1024)
void fps_kernel(const float* __restrict__ x, float* __restrict__ node) {
#pragma clang fp contract(off)
  const int b = blockIdx.x;
  const int t = threadIdx.x;
  const float4* xb = (const float4*)(x + (size_t)b * Nn * 4);
  extern __shared__ float2 yz[];  // [16][1024] transposed
  float px[16], mind[16];
  const int base = t * 16;
#pragma unroll
  for (int i = 0; i < 16; ++i) {
    float4 v = xb[base + i];
    px[i] = v.x;
    yz[i * 1024 + t] = (float2){v.y, v.z};
    mind[i] = 1e10f;
  }
  __shared__ __align__(16) unsigned long long kkey[2][16];
  float cx, cy, cz;
  {
    float4 v = xb[0];
    cx = v.x; cy = v.y; cz = v.z;
    if (t == 0) ((float4*)node)[b * Mn] = v;
  }
  __syncthreads();  // yz visible
  for (int s = 1; s < Mn; ++s) {
    // pass 1: distance + running min (exact np order, no contraction)
#pragma unroll
    for (int i = 0; i < 16; ++i) {
      float2 p = yz[i * 1024 + t];
      float dx = px[i] - cx;
      float dy = p.x - cy;
      float dz = p.y - cz;
      float qx = dx * dx;
      float qy = dy * dy;
      float qz = dz * dz;
      float d = (qx + qy) + qz;
      mind[i] = fminf(mind[i], d);
    }
    // pass 2: value max tree (v_max returns an input exactly; no NaN here)
    float a0 = fmaxf(mind[0], mind[1]);
    float a1 = fmaxf(mind[2], mind[3]);
    float a2 = fmaxf(mind[4], mind[5]);
    float a3 = fmaxf(mind[6], mind[7]);
    float a4 = fmaxf(mind[8], mind[9]);
    float a5 = fmaxf(mind[10], mind[11]);
    float a6 = fmaxf(mind[12], mind[13]);
    float a7 = fmaxf(mind[14], mind[15]);
    float b0 = fmaxf(a0, a1);
    float b1 = fmaxf(a2, a3);
    float b2 = fmaxf(a4, a5);
    float b3 = fmaxf(a6, a7);
    float bv = fmaxf(fmaxf(b0, b1), fmaxf(b2, b3));
    // pass 3: lowest matching lane-local index (descending scan)
    int isel = 0;
#pragma unroll
    for (int i = 15; i >= 0; --i)
      if (mind[i] == bv) isel = i;
    // wave reduce: value-only DPP max -> lane 63 -> ballot lowest tying lane
    float r = bv;
    r = dppmaxf<0x111>(r);  // row_shr:1
    r = dppmaxf<0x112>(r);  // row_shr:2
    r = dppmaxf<0x114>(r);  // row_shr:4
    r = dppmaxf<0x118>(r);  // row_shr:8
    r = dppmaxf<0x142>(r);  // row_bcast:15
    r = dppmaxf<0x143>(r);  // row_bcast:31
    float wmax = __int_as_float(__builtin_amdgcn_readlane(__float_as_int(r), 63));
    unsigned long long ball = __ballot(bv == wmax);
    int wl = __ffsll(ball) - 1;            // lowest tying lane
    int widx = __builtin_amdgcn_readlane(base + isel, wl);
    if ((t & 63) == 0) {
      kkey[s & 1][t >> 6] =
          ((unsigned long long)(__float_as_uint(wmax) | 0x80000000u) << 32) |
          (unsigned)(~widx);
    }
    __syncthreads();
    {
      // lane-parallel block max: lane reads kkey[t&15] (16 u64 over all 32
      // banks; lanes 16+ broadcast), 4-step xor-net max in 16-lane groups
      unsigned long long kk = kkey[s & 1][t & 15];
#pragma unroll
      for (int off = 1; off < 16; off <<= 1) {
        unsigned long long ok = __shfl_xor(kk, off, 16);
        kk = ok > kk ? ok : kk;
      }
      // uniform winner -> scalarized reload
      int wi = __builtin_amdgcn_readfirstlane((int)(~(unsigned)(kk & 0xFFFFFFFFu)));
      float4 nv = xb[wi];
      cx = nv.x; cy = nv.y; cz = nv.z;
      if (t == 0) ((float4*)node)[b * Mn + s] = nv;
    }
  }
}

// ------- kernel 2: top-64 kNN. sq terms NON-FMA (np materialized square);
// dot = BLAS/XLA sequential forward FMA: fma(z,z', fma(y,y', x*x'));
// combine (sqm+sqp) - 2*dot unfused. Stable lowest-index ties.
// Radix select BYTE-wise: 4 passes x 256 bins - same counts, same rank
// semantics, same threshold; half the scan work, fewer barriers, atomic
// contention spread over 256 addresses. -------
__global__ __launch_bounds__(256) void knn_kernel(const float* __restrict__ x,
                                                  const float* __restrict__ node,
                                                  const float* __restrict__ sqp,
                                                  const int* __restrict__ rand_idx,
                                                  int* __restrict__ sel) {
#pragma clang fp contract(off)
  const int bm = blockIdx.x;
  const int b = bm >> 9;
  const int t = threadIdx.x;
  const float4* xb = (const float4*)(x + (size_t)b * Nn * 4);
  const float* sq_b = sqp + b * Nn;
  float4 nd = ((const float4*)node)[bm];
  const float nx = nd.x, ny = nd.y, nz = nd.z;
  // node's own sq, same non-FMA form as sq_kernel (np reads it from the
  // same materialized array)
  const float sqmf = (nx * nx + ny * ny) + nz * nz;
  unsigned key[64];
#pragma unroll
  for (int i = 0; i < 64; ++i) {
    int n = t + (i << 8);
    float4 v = xb[n];
    // GEMM microkernel accumulation: acc = x*x' (rounded), acc = fma(y,y',acc),
    // acc = fma(z,z',acc)  — explicit fmaf, immune to contract(off)
    float dot = nx * v.x;
    dot = __builtin_fmaf(ny, v.y, dot);
    dot = __builtin_fmaf(nz, v.z, dot);
    float d2 = (sqmf + sq_b[n]) - 2.0f * dot;
    key[i] = fkey(d2);
  }
  // radix-select the rank-95 (0-indexed) key -> guard-banded superset
  __shared__ unsigned hist[256];
  __shared__ unsigned gsum[16];
  __shared__ unsigned sh_prefix;
  __shared__ int sh_r;
  unsigned prefix = 0, pmask = 0;
  int r = 95;
  for (int shift = 24; shift >= 0; shift -= 8) {
    hist[t] = 0;
    __syncthreads();
#pragma unroll
    for (int i = 0; i < 64; ++i) {
      if ((key[i] & pmask) == prefix) atomicAdd(&hist[(key[i] >> shift) & 255], 1u);
    }
    __syncthreads();
    if (t < 16) {
      unsigned ssum = 0;
#pragma unroll
      for (int j = 0; j < 16; ++j) ssum += hist[t * 16 + j];
      gsum[t] = ssum;
    }
    __syncthreads();
    if (t == 0) {
      int rr = r;
      unsigned g = 0;
      for (unsigned j = 0; j < 16; ++j) {
        int c = (int)gsum[j];
        if (rr < c) { g = j; break; }
        rr -= c;
      }
      unsigned bin = g * 16;
      for (unsigned j = 0; j < 16; ++j) {
        int c = (int)hist[g * 16 + j];
        if (rr < c) { bin = g * 16 + j; break; }
        rr -= c;
      }
      sh_prefix = prefix | (bin << shift);
      sh_r = rr;
    }
    __syncthreads();
    prefix = sh_prefix;
    r = sh_r;
    pmask |= (0xFFu << shift);
  }
  const unsigned T = prefix;  // collect all keys <= T (>=96 candidates; cap 128)
  __shared__ int cnt;
  __shared__ unsigned long long karr[128];
  if (t == 0) cnt = 0;
  __syncthreads();
#pragma unroll
  for (int i = 0; i < 64; ++i) {
    if (key[i] <= T) {
      int pos = atomicAdd(&cnt, 1);
      if (pos < 128) {
        unsigned n = (unsigned)(t + (i << 8));
        // idx in low bits: ascending sort => equal d2 resolved LOWEST index first
        karr[pos] = ((unsigned long long)key[i] << 32) | n;
      }
    }
  }
  __syncthreads();
  const int nc = cnt < 128 ? cnt : 128;
  if (t < 128 && t >= nc) karr[t] = ~0ull;
  // 128-wide bitonic sort ascending
  for (int k = 2; k <= 128; k <<= 1) {
    for (int j = k >> 1; j > 0; j >>= 1) {
      __syncthreads();
      if (t < 64) {
        int i = ((t & ~(j - 1)) << 1) | (t & (j - 1));
        int ip = i | j;
        unsigned long long ka = karr[i], kb = karr[ip];
        bool asc = ((i & k) == 0);
        if ((ka > kb) == asc) { karr[i] = kb; karr[ip] = ka; }
      }
    }
  }
  __syncthreads();
  if (t < 32) {
    int ri = rand_idx[t];  // in [0,64)
    sel[bm * 32 + t] = (int)(unsigned)(karr[ri] & 0xFFFFFFFFu);
  }
}

// ---- top-8 over 32 candidates, lowest-idx ties (fp64 keys) ----
__device__ __forceinline__ void topk8(const unsigned long long* row, unsigned char* nb) {
  unsigned long long bk[8];
  unsigned char bi[8];
#pragma unroll
  for (int k = 0; k < 8; ++k) { bk[k] = ~0ull; bi[k] = 255; }
  for (int q = 0; q < 32; ++q) {
    unsigned long long kv = row[q];
    if (kv < bk[7]) {
      bk[7] = kv; bi[7] = (unsigned char)q;
#pragma unroll
      for (int k = 6; k >= 0; --k) {
        if (bk[k + 1] < bk[k]) {
          unsigned long long tk = bk[k]; bk[k] = bk[k + 1]; bk[k + 1] = tk;
          unsigned char ti = bi[k]; bi[k] = bi[k + 1]; bi[k + 1] = ti;
        }
      }
    }
  }
#pragma unroll
  for (int k = 0; k < 8; ++k) nb[k] = bi[k];
}

// ---------------- kernel 3: fused group pipeline ----------------
__global__ __launch_bounds__(256) void group_kernel(
    const float* __restrict__ x, const float* __restrict__ node,
    const int* __restrict__ sel, const float* __restrict__ w_e1,
    const float* __restrict__ g1, const float* __restrict__ b1,
    const float* __restrict__ w_e2, const float* __restrict__ g2,
    const float* __restrict__ b2, float* __restrict__ out,
    float* __restrict__ gcf) {
#pragma clang fp contract(off)
  const int bm = blockIdx.x;
  const int b = bm >> 9;
  const int m = bm & 511;
  const int t = threadIdx.x;

  __shared__ float cl[32][13];
  __shared__ float h1t[64][36];
  __shared__ float h1p[32][68];
  __shared__ unsigned char nbr[32][8];
  __shared__ double sqs[32];
  __shared__ float part[4][32];
  __shared__ float aws[32];
  __shared__ union U {
    struct {
      unsigned long long keys[32][32];
      float we_a[12][64];
      float we_d[12][64];
      float a1[32][65];
      float cd1[32][65];
    } s;
    float a2[32 * 256];
  } u;

  const float4* xb = (const float4*)(x + (size_t)b * Nn * 4);
  const float4 ndv = ((const float4*)node)[bm];

  if (t < 32) {
    int n = sel[bm * 32 + t];
    float4 v = xb[n];
    float rx = v.x - ndv.x;
    float ry = v.y - ndv.y;
    float rz = v.z - ndv.z;
    float ds = (rx * rx + ry * ry) + rz * rz;
    ds = __fsqrt_rn(ds);
    cl[t][0] = ndv.x; cl[t][1] = ndv.y; cl[t][2] = ndv.z; cl[t][3] = ndv.w;
    cl[t][4] = v.x;   cl[t][5] = v.y;   cl[t][6] = v.z;   cl[t][7] = v.w;
    cl[t][8] = rx;    cl[t][9] = ry;    cl[t][10] = rz;   cl[t][11] = ds;
  }
  for (int i = t; i < 768; i += 256) {
    int row = i >> 6, d = i & 63;
    float wa = w_e1[row * 64 + d];
    float wb = w_e1[(row + 12) * 64 + d];
    u.s.we_a[row][d] = wa;
    u.s.we_d[row][d] = wb - wa;
  }
  __syncthreads();

  for (int i = t; i < 384; i += 256) {
    int c = i >> 5, p = i & 31;
    out[O_RC + (((size_t)(b * 12 + c) * 512) + m) * 32 + p] = cl[p][c];
  }
  if (t < 32) {
    double q[12];
#pragma unroll
    for (int c = 0; c < 12; ++c) {
      double cv = (double)cl[t][c];
      q[c] = cv * cv;
    }
    double s01 = q[0] + q[1];
    double s23 = q[2] + q[3];
    double s45 = q[4] + q[5];
    double s67 = q[6] + q[7];
    double s = (s01 + s23) + (s45 + s67);
    s = s + q[8];
    s = s + q[9];
    s = s + q[10];
    s = s + q[11];
    sqs[t] = s;
  }
  __syncthreads();

  // pairwise d2 (12-d, fp64 order-exact) -> keys
  {
    int p = t >> 3, q0 = (t & 7) << 2;
#pragma unroll
    for (int qq = 0; qq < 4; ++qq) {
      int q = q0 + qq;
      double dot = 0.0;
#pragma unroll
      for (int c = 0; c < 12; ++c)
        dot = dot + (double)cl[p][c] * (double)cl[q][c];
      double d2 = (sqs[p] + sqs[q]) - 2.0 * dot;
      u.s.keys[p][q] = dkey(d2);
    }
  }
  __syncthreads();

  if (t < 32) topk8(&u.s.keys[t][0], &nbr[t][0]);
  {
    int d = t & 63, pg = (t >> 6) << 3;
#pragma unroll
    for (int pp = 0; pp < 8; ++pp) {
      int p = pg + pp;
      float aA = 0.f, aD = 0.f;
#pragma unroll
      for (int c = 0; c < 12; ++c) {
        float xv = cl[p][c];
        aA = fmaf(xv, u.s.we_a[c][d], aA);
        aD = fmaf(xv, u.s.we_d[c][d], aD);
      }
      u.s.a1[p][d] = aA;
      u.s.cd1[p][d] = aD;
    }
  }
  __syncthreads();

  {
    int d = t & 63, pg = (t >> 6) << 3;
    float g1v = g1[d], b1v = b1[d];
#pragma unroll
    for (int pp = 0; pp < 8; ++pp) {
      int p = pg + pp;
      float cd = u.s.cd1[p][d];
      float hm = -1e30f;
#pragma unroll
      for (int k = 0; k < 8; ++k) {
        int j = nbr[p][k];
        float hv = fmaf(g1v, u.s.a1[j][d] + cd, b1v);
        hv = fmaxf(hv, 0.f);
        hm = fmaxf(hm, hv);
      }
      h1t[d][p] = hm;
      h1p[p][d] = hm;
    }
  }
  __syncthreads();

  if (t < 32) {
    double r[8];
#pragma unroll
    for (int j = 0; j < 8; ++j) {
      double hv = (double)h1p[t][j];
      r[j] = hv * hv;
    }
#pragma unroll
    for (int blk = 1; blk < 8; ++blk) {
#pragma unroll
      for (int j = 0; j < 8; ++j) {
        double hv = (double)h1p[t][blk * 8 + j];
        r[j] = r[j] + hv * hv;
      }
    }
    double s01 = r[0] + r[1];
    double s23 = r[2] + r[3];
    double s45 = r[4] + r[5];
    double s67 = r[6] + r[7];
    sqs[t] = (s01 + s23) + (s45 + s67);
  }
  __syncthreads();

  {
    int p = t >> 3, q0 = (t & 7) << 2;
#pragma unroll
    for (int qq = 0; qq < 4; ++qq) {
      int q = q0 + qq;
      double dot = 0.0;
      for (int c = 0; c < 64; ++c)
        dot = dot + (double)h1p[p][c] * (double)h1p[q][c];
      double d2 = (sqs[p] + sqs[q]) - 2.0 * dot;
      u.s.keys[p][q] = dkey(d2);
    }
  }
  __syncthreads();

  if (t < 32) topk8(&u.s.keys[t][0], &nbr[t][0]);
  __syncthreads();

  float accD[32];
  float embv[32];
  {
    float accA[32];
#pragma unroll
    for (int p = 0; p < 32; ++p) { accA[p] = 0.f; accD[p] = 0.f; }
    for (int c = 0; c < 64; ++c) {
      float wt = w_e2[c * 256 + t];
      float wb = w_e2[(c + 64) * 256 + t];
      float wd = wb - wt;
      const float4* row = (const float4*)&h1t[c][0];
#pragma unroll
      for (int p4 = 0; p4 < 8; ++p4) {
        float4 hv = row[p4];
        accA[4 * p4 + 0] = fmaf(hv.x, wt, accA[4 * p4 + 0]);
        accA[4 * p4 + 1] = fmaf(hv.y, wt, accA[4 * p4 + 1]);
        accA[4 * p4 + 2] = fmaf(hv.z, wt, accA[4 * p4 + 2]);
        accA[4 * p4 + 3] = fmaf(hv.w, wt, accA[4 * p4 + 3]);
        accD[4 * p4 + 0] = fmaf(hv.x, wd, accD[4 * p4 + 0]);
        accD[4 * p4 + 1] = fmaf(hv.y, wd, accD[4 * p4 + 1]);
        accD[4 * p4 + 2] = fmaf(hv.z, wd, accD[4 * p4 + 2]);
        accD[4 * p4 + 3] = fmaf(hv.w, wd, accD[4 * p4 + 3]);
      }
    }
#pragma unroll
    for (int p = 0; p < 32; ++p) u.a2[p * 256 + t] = accA[p];
  }
  __syncthreads();
  {
    float g2v = g2[t], b2v = b2[t];
#pragma unroll
    for (int p = 0; p < 32; ++p) {
      float cd = accD[p];
      float e = -1e30f;
#pragma unroll
      for (int k = 0; k < 8; ++k) {
        int j = nbr[p][k];
        float hv = fmaf(g2v, u.a2[j * 256 + t] + cd, b2v);
        hv = fmaxf(hv, 0.f);
        e = fmaxf(e, hv);
      }
      embv[p] = e;
    }
  }

#pragma unroll
  for (int p = 0; p < 32; ++p) {
    float v = embv[p];
#pragma unroll
    for (int off = 32; off > 0; off >>= 1) v = fmaxf(v, __shfl_xor(v, off));
    if ((t & 63) == 0) part[t >> 6][p] = v;
  }
  __syncthreads();

  if (t < 32) {
    float x1 = fmaxf(fmaxf(part[0][t], part[1][t]), fmaxf(part[2][t], part[3][t]));
    float mx = x1;
#pragma unroll
    for (int off = 16; off > 0; off >>= 1) mx = fmaxf(mx, __shfl_xor(mx, off));
    float ex = expf(x1 - mx);
    float sm = ex;
#pragma unroll
    for (int off = 16; off > 0; off >>= 1) sm += __shfl_xor(sm, off);
    float aw = ex / sm;
    aws[t] = aw;
#pragma unroll
    for (int c = 0; c < 3; ++c) {
      float kv = aw * cl[t][4 + c];
#pragma unroll
      for (int off = 16; off > 0; off >>= 1) kv += __shfl_xor(kv, off);
      if (t == 0) out[((size_t)(b * 3 + c)) * 512 + m] = kv;
    }
  }
  __syncthreads();

  {
    float gsum = 0.f;
    size_t abase = (size_t)O_AFM + (((size_t)(b * 256 + t)) * 512 + m) * 32;
    float4* ap = (float4*)(out + abase);
#pragma unroll
    for (int p4 = 0; p4 < 8; ++p4) {
      float4 o;
      o.x = embv[4 * p4 + 0] * aws[4 * p4 + 0];
      o.y = embv[4 * p4 + 1] * aws[4 * p4 + 1];
      o.z = embv[4 * p4 + 2] * aws[4 * p4 + 2];
      o.w = embv[4 * p4 + 3] * aws[4 * p4 + 3];
      gsum += o.x; gsum += o.y; gsum += o.z; gsum += o.w;
      ap[p4] = o;
    }
    gcf[((size_t)(b * 256 + t)) * 512 + m] = gsum;
  }
}

// ---------------- kernel 4: MLP head ----------------
__global__ __launch_bounds__(256) void mlp_kernel(
    const float* __restrict__ gcf, const float* __restrict__ w_m1,
    const float* __restrict__ bm1, const float* __restrict__ gm1,
    const float* __restrict__ bbm1, const float* __restrict__ w_m2,
    const float* __restrict__ bm2, const float* __restrict__ gm2,
    const float* __restrict__ bbm2, const float* __restrict__ w_m3,
    const float* __restrict__ bm3, float* __restrict__ out) {
  const int blk = blockIdx.x;
  const int b = blk >> 4;
  const int m0 = (blk & 15) << 5;
  const int t = threadIdx.x;
  __shared__ float sbuf[256 * 36];

#pragma unroll
  for (int i = 0; i < 32; ++i) {
    int c = (t >> 5) + (i << 3);
    int j = t & 31;
    sbuf[c * 36 + j] = gcf[((size_t)(b * 256 + c)) * 512 + m0 + j];
  }
  __syncthreads();

  float acc[32];
#pragma unroll
  for (int j = 0; j < 32; ++j) acc[j] = 0.f;
  for (int c = 0; c < 256; ++c) {
    float wv = w_m1[c * 256 + t];
    const float4* row = (const float4*)&sbuf[c * 36];
#pragma unroll
    for (int j4 = 0; j4 < 8; ++j4) {
      float4 g4 = row[j4];
      acc[4 * j4 + 0] = fmaf(g4.x, wv, acc[4 * j4 + 0]);
      acc[4 * j4 + 1] = fmaf(g4.y, wv, acc[4 * j4 + 1]);
      acc[4 * j4 + 2] = fmaf(g4.z, wv, acc[4 * j4 + 2]);
      acc[4 * j4 + 3] = fmaf(g4.w, wv, acc[4 * j4 + 3]);
    }
  }
  float y[32];
  {
    float gv = gm1[t], bv = bm1[t], bbv = bbm1[t];
#pragma unroll
    for (int j = 0; j < 32; ++j) y[j] = fmaxf(fmaf(gv, acc[j] + bv, bbv), 0.f);
  }
  __syncthreads();
#pragma unroll
  for (int j = 0; j < 32; ++j) sbuf[t * 36 + j] = y[j];
  __syncthreads();

#pragma unroll
  for (int j = 0; j < 32; ++j) acc[j] = 0.f;
  for (int c = 0; c < 256; ++c) {
    float wv = w_m2[c * 256 + t];
    const float4* row = (const float4*)&sbuf[c * 36];
#pragma unroll
    for (int j4 = 0; j4 < 8; ++j4) {
      float4 g4 = row[j4];
      acc[4 * j4 + 0] = fmaf(g4.x, wv, acc[4 * j4 + 0]);
      acc[4 * j4 + 1] = fmaf(g4.y, wv, acc[4 * j4 + 1]);
      acc[4 * j4 + 2] = fmaf(g4.z, wv, acc[4 * j4 + 2]);
      acc[4 * j4 + 3] = fmaf(g4.w, wv, acc[4 * j4 + 3]);
    }
  }
  {
    float gv = gm2[t], bv = bm2[t], bbv = bbm2[t];
#pragma unroll
    for (int j = 0; j < 32; ++j) y[j] = fmaxf(fmaf(gv, acc[j] + bv, bbv), 0.f);
  }
  __syncthreads();
  {
    float w3v = w_m3[t];
#pragma unroll
    for (int j = 0; j < 32; ++j) sbuf[t * 36 + j] = y[j] * w3v;
  }
  __syncthreads();
  if (t < 32) {
    float s = 0.f;
    for (int d = 0; d < 256; ++d) s += sbuf[d * 36 + t];
    s += bm3[0];
    float sal = log1pf(expf(-fabsf(s))) + fmaxf(s, 0.f) + 0.001f;
    out[O_SAL + (size_t)b * 512 + m0 + t] = sal;
  }
}

extern "C" void kernel_launch(void* const* d_in, const int* in_sizes, int n_in,
                              void* d_out, int out_size, void* d_ws, size_t ws_size,
                              hipStream_t stream) {
  (void)in_sizes; (void)n_in; (void)out_size; (void)ws_size;
  const float* x = (const float*)d_in[0];
  const int* rand_idx = (const int*)d_in[1];
  const float* w_e1 = (const float*)d_in[2];
  const float* g1 = (const float*)d_in[3];
  const float* b1 = (const float*)d_in[4];
  const float* w_e2 = (const float*)d_in[5];
  const float* g2 = (const float*)d_in[6];
  const float* b2 = (const float*)d_in[7];
  const float* w_m1 = (const float*)d_in[8];
  const float* bm1 = (const float*)d_in[9];
  const float* gm1 = (const float*)d_in[10];
  const float* bbm1 = (const float*)d_in[11];
  const float* w_m2 = (const float*)d_in[12];
  const float* bm2 = (const float*)d_in[13];
  const float* gm2 = (const float*)d_in[14];
  const float* bbm2 = (const float*)d_in[15];
  const float* w_m3 = (const float*)d_in[16];
  const float* bm3 = (const float*)d_in[17];
  float* out = (float*)d_out;
  char* ws = (char*)d_ws;

  float* node = (float*)ws;                             // 32 KB
  float* sqp = (float*)(ws + 32768);                    // 256 KB
  int* sel = (int*)(ws + 32768 + 262144);               // 256 KB
  float* gcf = (float*)(ws + 32768 + 262144 + 262144);  // 2 MB

  sq_kernel<<<256, 256, 0, stream>>>(x, sqp);
  fps_kernel<<<Bn, 1024, 16384 * sizeof(float2), stream>>>(x, node);
  knn_kernel<<<Bn * Mn, 256, 0, stream>>>(x, node, sqp, rand_idx, sel);
  group_kernel<<<Bn * Mn, 256, 0, stream>>>(x, node, sel, w_e1, g1, b1, w_e2,
                                            g2, b2, out, gcf);
  mlp_kernel<<<64, 256, 0, stream>>>(gcf, w_m1, bm1, gm1, bbm1, w_m2, bm2, gm2,
                                     bbm2, w_m3, bm3, out);
}

// Round 9
// 1670.798 us; speedup vs baseline: 1.0406x; 1.0325x over previous
//
#include <hip/hip_runtime.h>
#include <cstdint>

#define Bn 4
#define Nn 16384
#define Mn 512
#define Kn 32

// output offsets (floats)
#define O_SAL 6144
#define O_RC  8192
#define O_AFM 794624

__device__ __forceinline__ unsigned fkey(float f) {
  unsigned b = __float_as_uint(f);
  return (b & 0x80000000u) ? ~b : (b | 0x80000000u);
}

__device__ __forceinline__ unsigned long long dkey(double d) {
  unsigned long long b = (unsigned long long)__double_as_longlong(d);
  return (b & 0x8000000000000000ull) ? ~b : (b | 0x8000000000000000ull);
}

// ---- kernel 0: per-point squared norm (np: materialized square + seq sum, NO FMA) ----
__global__ __launch_bounds__(256) void sq_kernel(const float* __restrict__ x,
                                                 float* __restrict__ sqp) {
#pragma clang fp contract(off)
  int i = blockIdx.x * 256 + threadIdx.x;  // < B*N
  float4 v = ((const float4*)x)[i];
  float qx = v.x * v.x;
  float qy = v.y * v.y;
  float qz = v.z * v.z;
  sqp[i] = (qx + qy) + qz;
}

// DPP max step: moved = lane-shuffled v (old = self fallback), then max.
// Values are >= 0 here, so either bound_ctrl semantic (old or 0) is safe.
template <int CTRL>
__device__ __forceinline__ float dppmaxf(float v) {
  int m = __builtin_amdgcn_update_dpp(__float_as_int(v), __float_as_int(v),
                                      CTRL, 0xf, 0xf, false);
  return fmaxf(v, __int_as_float(m));
}

// ---------------- kernel 1: farthest point sampling (fp32, NO contraction) ----------------
// EXACT revert to the round-5 version - the best measured fps (888us).
// 8-round record: r5 (this code, scratch spills and all) 888 < r1 938 <
// r7 multiblock 969 < r8 LDS-resident 985. Emitted VALU/thread/step ~460
// in every variant (from VALUBusy x dur) - the compiler's 2x inflation is
// invariant to spills/LDS/occupancy attributes, so per-step ~1.73us is this
// structure's floor. Banked; optimization budget moved to knn/group.
// Math: contract(off), (qx+qy)+qz, fminf chain, exact-equality lowest-index
// ties; DPP value-max wave reduce; lane-parallel 16-key block tail.
__global__ __launch_bounds__(1024)
__attribute__((amdgpu_waves_per_eu(4, 4)))
void fps_kernel(const float* __restrict__ x, float* __restrict__ node) {
#pragma clang fp contract(off)
  const int b = blockIdx.x;
  const int t = threadIdx.x;
  const float4* xb = (const float4*)(x + (size_t)b * Nn * 4);
  float px[16], py[16], pz[16], mind[16];
  const int base = t * 16;
#pragma unroll
  for (int i = 0; i < 16; ++i) {
    float4 v = xb[base + i];
    px[i] = v.x; py[i] = v.y; pz[i] = v.z;
    mind[i] = 1e10f;
  }
  __shared__ __align__(16) unsigned long long kkey[2][16];
  float cx, cy, cz;
  {
    float4 v = xb[0];
    cx = v.x; cy = v.y; cz = v.z;
    if (t == 0) ((float4*)node)[b * Mn] = v;
  }
  for (int s = 1; s < Mn; ++s) {
    // pass 1: distance + running min (exact np order, no contraction)
#pragma unroll
    for (int i = 0; i < 16; ++i) {
      float dx = px[i] - cx;
      float dy = py[i] - cy;
      float dz = pz[i] - cz;
      float qx = dx * dx;
      float qy = dy * dy;
      float qz = dz * dz;
      float d = (qx + qy) + qz;
      mind[i] = fminf(mind[i], d);
    }
    // pass 2: value max tree (v_max returns an input exactly; no NaN here)
    float a0 = fmaxf(mind[0], mind[1]);
    float a1 = fmaxf(mind[2], mind[3]);
    float a2 = fmaxf(mind[4], mind[5]);
    float a3 = fmaxf(mind[6], mind[7]);
    float a4 = fmaxf(mind[8], mind[9]);
    float a5 = fmaxf(mind[10], mind[11]);
    float a6 = fmaxf(mind[12], mind[13]);
    float a7 = fmaxf(mind[14], mind[15]);
    float b0 = fmaxf(a0, a1);
    float b1 = fmaxf(a2, a3);
    float b2 = fmaxf(a4, a5);
    float b3 = fmaxf(a6, a7);
    float bv = fmaxf(fmaxf(b0, b1), fmaxf(b2, b3));
    // pass 3: lowest matching lane-local index (descending scan)
    int isel = 0;
#pragma unroll
    for (int i = 15; i >= 0; --i)
      if (mind[i] == bv) isel = i;
    // wave reduce: value-only DPP max -> lane 63 -> uniform
    float r = bv;
    r = dppmaxf<0x111>(r);  // row_shr:1
    r = dppmaxf<0x112>(r);  // row_shr:2
    r = dppmaxf<0x114>(r);  // row_shr:4
    r = dppmaxf<0x118>(r);  // row_shr:8
    r = dppmaxf<0x142>(r);  // row_bcast:15
    r = dppmaxf<0x143>(r);  // row_bcast:31
    float wmax = __int_as_float(__builtin_amdgcn_readlane(__float_as_int(r), 63));
    unsigned long long ball = __ballot(bv == wmax);
    int wl = __ffsll(ball) - 1;            // lowest tying lane
    int widx = __builtin_amdgcn_readlane(base + isel, wl);
    if ((t & 63) == 0) {
      kkey[s & 1][t >> 6] =
          ((unsigned long long)(__float_as_uint(wmax) | 0x80000000u) << 32) |
          (unsigned)(~widx);
    }
    __syncthreads();
    {
      // lane-parallel block max: lane reads kkey[t&15] (16 u64 = all 32
      // banks; lanes 16+ broadcast), 4-step xor-net max within 16-lane groups
      unsigned long long kk = kkey[s & 1][t & 15];
#pragma unroll
      for (int off = 1; off < 16; off <<= 1) {
        unsigned long long ok = __shfl_xor(kk, off, 16);
        kk = ok > kk ? ok : kk;
      }
      // uniform across the block -> scalarize the winner reload
      int wi = __builtin_amdgcn_readfirstlane((int)(~(unsigned)(kk & 0xFFFFFFFFu)));
      float4 nv = xb[wi];
      cx = nv.x; cy = nv.y; cz = nv.z;
      if (t == 0) ((float4*)node)[b * Mn + s] = nv;
    }
  }
}

// ------- kernel 2: top-64 kNN. sq terms NON-FMA (np materialized square);
// dot = BLAS/XLA sequential forward FMA: fma(z,z', fma(y,y', x*x'));
// combine (sqm+sqp) - 2*dot unfused. Stable lowest-index ties.
// Radix select BYTE-wise, with WAVE-REPLICATED histograms: d2 keys
// concentrate in ~8-16 exponent bins, so pass 1's 16384 same-address LDS
// atomicAdds serialize. hist[bin][wave] (4 copies in 4 consecutive banks)
// cuts hot-bin serialization 4x. Counts/threshold/rank semantics identical.
__global__ __launch_bounds__(256) void knn_kernel(const float* __restrict__ x,
                                                  const float* __restrict__ node,
                                                  const float* __restrict__ sqp,
                                                  const int* __restrict__ rand_idx,
                                                  int* __restrict__ sel) {
#pragma clang fp contract(off)
  const int bm = blockIdx.x;
  const int b = bm >> 9;
  const int t = threadIdx.x;
  const int w = t >> 6;  // wave id 0..3
  const float4* xb = (const float4*)(x + (size_t)b * Nn * 4);
  const float* sq_b = sqp + b * Nn;
  float4 nd = ((const float4*)node)[bm];
  const float nx = nd.x, ny = nd.y, nz = nd.z;
  // node's own sq, same non-FMA form as sq_kernel (np reads it from the
  // same materialized array)
  const float sqmf = (nx * nx + ny * ny) + nz * nz;
  unsigned key[64];
#pragma unroll
  for (int i = 0; i < 64; ++i) {
    int n = t + (i << 8);
    float4 v = xb[n];
    // GEMM microkernel accumulation: acc = x*x' (rounded), acc = fma(y,y',acc),
    // acc = fma(z,z',acc)  — explicit fmaf, immune to contract(off)
    float dot = nx * v.x;
    dot = __builtin_fmaf(ny, v.y, dot);
    dot = __builtin_fmaf(nz, v.z, dot);
    float d2 = (sqmf + sq_b[n]) - 2.0f * dot;
    key[i] = fkey(d2);
  }
  // radix-select the rank-95 (0-indexed) key -> guard-banded superset
  __shared__ unsigned hist[256 * 4];  // [bin][wave] interleaved
  __shared__ unsigned gsum[16];
  __shared__ unsigned sh_prefix;
  __shared__ int sh_r;
  unsigned prefix = 0, pmask = 0;
  int r = 95;
  for (int shift = 24; shift >= 0; shift -= 8) {
    ((uint4*)hist)[t] = (uint4){0u, 0u, 0u, 0u};
    __syncthreads();
#pragma unroll
    for (int i = 0; i < 64; ++i) {
      if ((key[i] & pmask) == prefix)
        atomicAdd(&hist[(((key[i] >> shift) & 255) << 2) + w], 1u);
    }
    __syncthreads();
    if (t < 16) {
      unsigned ssum = 0;
#pragma unroll
      for (int j = 0; j < 64; ++j) ssum += hist[(t << 6) + j];
      gsum[t] = ssum;
    }
    __syncthreads();
    if (t == 0) {
      int rr = r;
      unsigned g = 0;
      for (unsigned j = 0; j < 16; ++j) {
        int c = (int)gsum[j];
        if (rr < c) { g = j; break; }
        rr -= c;
      }
      unsigned bin = g * 16;
      for (unsigned j = 0; j < 16; ++j) {
        unsigned bb = g * 16 + j;
        int c = (int)(hist[(bb << 2)] + hist[(bb << 2) + 1] +
                      hist[(bb << 2) + 2] + hist[(bb << 2) + 3]);
        if (rr < c) { bin = bb; break; }
        rr -= c;
      }
      sh_prefix = prefix | (bin << shift);
      sh_r = rr;
    }
    __syncthreads();
    prefix = sh_prefix;
    r = sh_r;
    pmask |= (0xFFu << shift);
  }
  const unsigned T = prefix;  // collect all keys <= T (>=96 candidates; cap 128)
  __shared__ int cnt;
  __shared__ unsigned long long karr[128];
  if (t == 0) cnt = 0;
  __syncthreads();
#pragma unroll
  for (int i = 0; i < 64; ++i) {
    if (key[i] <= T) {
      int pos = atomicAdd(&cnt, 1);
      if (pos < 128) {
        unsigned n = (unsigned)(t + (i << 8));
        // idx in low bits: ascending sort => equal d2 resolved LOWEST index first
        karr[pos] = ((unsigned long long)key[i] << 32) | n;
      }
    }
  }
  __syncthreads();
  const int nc = cnt < 128 ? cnt : 128;
  if (t < 128 && t >= nc) karr[t] = ~0ull;
  // 128-wide bitonic sort ascending
  for (int k = 2; k <= 128; k <<= 1) {
    for (int j = k >> 1; j > 0; j >>= 1) {
      __syncthreads();
      if (t < 64) {
        int i = ((t & ~(j - 1)) << 1) | (t & (j - 1));
        int ip = i | j;
        unsigned long long ka = karr[i], kb = karr[ip];
        bool asc = ((i & k) == 0);
        if ((ka > kb) == asc) { karr[i] = kb; karr[ip] = ka; }
      }
    }
  }
  __syncthreads();
  if (t < 32) {
    int ri = rand_idx[t];  // in [0,64)
    sel[bm * 32 + t] = (int)(unsigned)(karr[ri] & 0xFFFFFFFFu);
  }
}

// ---- top-8 over 32 candidates, lowest-idx ties (fp64 keys) ----
__device__ __forceinline__ void topk8(const unsigned long long* row, unsigned char* nb) {
  unsigned long long bk[8];
  unsigned char bi[8];
#pragma unroll
  for (int k = 0; k < 8; ++k) { bk[k] = ~0ull; bi[k] = 255; }
  for (int q = 0; q < 32; ++q) {
    unsigned long long kv = row[q];
    if (kv < bk[7]) {
      bk[7] = kv; bi[7] = (unsigned char)q;
#pragma unroll
      for (int k = 6; k >= 0; --k) {
        if (bk[k + 1] < bk[k]) {
          unsigned long long tk = bk[k]; bk[k] = bk[k + 1]; bk[k + 1] = tk;
          unsigned char ti = bi[k]; bi[k] = bi[k + 1]; bi[k + 1] = ti;
        }
      }
    }
  }
#pragma unroll
  for (int k = 0; k < 8; ++k) nb[k] = bi[k];
}

// ---------------- kernel 3: fused group pipeline ----------------
__global__ __launch_bounds__(256) void group_kernel(
    const float* __restrict__ x, const float* __restrict__ node,
    const int* __restrict__ sel, const float* __restrict__ w_e1,
    const float* __restrict__ g1, const float* __restrict__ b1,
    const float* __restrict__ w_e2, const float* __restrict__ g2,
    const float* __restrict__ b2, float* __restrict__ out,
    float* __restrict__ gcf) {
#pragma clang fp contract(off)
  const int bm = blockIdx.x;
  const int b = bm >> 9;
  const int m = bm & 511;
  const int t = threadIdx.x;

  __shared__ float cl[32][13];
  __shared__ float h1t[64][36];
  __shared__ float h1p[32][68];
  __shared__ unsigned char nbr[32][8];
  __shared__ double sqs[32];
  __shared__ float part[4][32];
  __shared__ float aws[32];
  __shared__ union U {
    struct {
      unsigned long long keys[32][32];
      float we_a[12][64];
      float we_d[12][64];
      float a1[32][65];
      float cd1[32][65];
    } s;
    float a2[32 * 256];
  } u;

  const float4* xb = (const float4*)(x + (size_t)b * Nn * 4);
  const float4 ndv = ((const float4*)node)[bm];

  if (t < 32) {
    int n = sel[bm * 32 + t];
    float4 v = xb[n];
    float rx = v.x - ndv.x;
    float ry = v.y - ndv.y;
    float rz = v.z - ndv.z;
    float ds = (rx * rx + ry * ry) + rz * rz;
    ds = __fsqrt_rn(ds);
    cl[t][0] = ndv.x; cl[t][1] = ndv.y; cl[t][2] = ndv.z; cl[t][3] = ndv.w;
    cl[t][4] = v.x;   cl[t][5] = v.y;   cl[t][6] = v.z;   cl[t][7] = v.w;
    cl[t][8] = rx;    cl[t][9] = ry;    cl[t][10] = rz;   cl[t][11] = ds;
  }
  for (int i = t; i < 768; i += 256) {
    int row = i >> 6, d = i & 63;
    float wa = w_e1[row * 64 + d];
    float wb = w_e1[(row + 12) * 64 + d];
    u.s.we_a[row][d] = wa;
    u.s.we_d[row][d] = wb - wa;
  }
  __syncthreads();

  for (int i = t; i < 384; i += 256) {
    int c = i >> 5, p = i & 31;
    out[O_RC + (((size_t)(b * 12 + c) * 512) + m) * 32 + p] = cl[p][c];
  }
  if (t < 32) {
    double q[12];
#pragma unroll
    for (int c = 0; c < 12; ++c) {
      double cv = (double)cl[t][c];
      q[c] = cv * cv;
    }
    double s01 = q[0] + q[1];
    double s23 = q[2] + q[3];
    double s45 = q[4] + q[5];
    double s67 = q[6] + q[7];
    double s = (s01 + s23) + (s45 + s67);
    s = s + q[8];
    s = s + q[9];
    s = s + q[10];
    s = s + q[11];
    sqs[t] = s;
  }
  __syncthreads();

  // pairwise d2 (12-d, fp64 order-exact) -> keys
  {
    int p = t >> 3, q0 = (t & 7) << 2;
#pragma unroll
    for (int qq = 0; qq < 4; ++qq) {
      int q = q0 + qq;
      double dot = 0.0;
#pragma unroll
      for (int c = 0; c < 12; ++c)
        dot = dot + (double)cl[p][c] * (double)cl[q][c];
      double d2 = (sqs[p] + sqs[q]) - 2.0 * dot;
      u.s.keys[p][q] = dkey(d2);
    }
  }
  __syncthreads();

  if (t < 32) topk8(&u.s.keys[t][0], &nbr[t][0]);
  {
    int d = t & 63, pg = (t >> 6) << 3;
#pragma unroll
    for (int pp = 0; pp < 8; ++pp) {
      int p = pg + pp;
      float aA = 0.f, aD = 0.f;
#pragma unroll
      for (int c = 0; c < 12; ++c) {
        float xv = cl[p][c];
        aA = fmaf(xv, u.s.we_a[c][d], aA);
        aD = fmaf(xv, u.s.we_d[c][d], aD);
      }
      u.s.a1[p][d] = aA;
      u.s.cd1[p][d] = aD;
    }
  }
  __syncthreads();

  {
    int d = t & 63, pg = (t >> 6) << 3;
    float g1v = g1[d], b1v = b1[d];
#pragma unroll
    for (int pp = 0; pp < 8; ++pp) {
      int p = pg + pp;
      float cd = u.s.cd1[p][d];
      float hm = -1e30f;
#pragma unroll
      for (int k = 0; k < 8; ++k) {
        int j = nbr[p][k];
        float hv = fmaf(g1v, u.s.a1[j][d] + cd, b1v);
        hv = fmaxf(hv, 0.f);
        hm = fmaxf(hm, hv);
      }
      h1t[d][p] = hm;
      h1p[p][d] = hm;
    }
  }
  __syncthreads();

  if (t < 32) {
    double r[8];
#pragma unroll
    for (int j = 0; j < 8; ++j) {
      double hv = (double)h1p[t][j];
      r[j] = hv * hv;
    }
#pragma unroll
    for (int blk = 1; blk < 8; ++blk) {
#pragma unroll
      for (int j = 0; j < 8; ++j) {
        double hv = (double)h1p[t][blk * 8 + j];
        r[j] = r[j] + hv * hv;
      }
    }
    double s01 = r[0] + r[1];
    double s23 = r[2] + r[3];
    double s45 = r[4] + r[5];
    double s67 = r[6] + r[7];
    sqs[t] = (s01 + s23) + (s45 + s67);
  }
  __syncthreads();

  {
    int p = t >> 3, q0 = (t & 7) << 2;
#pragma unroll
    for (int qq = 0; qq < 4; ++qq) {
      int q = q0 + qq;
      double dot = 0.0;
      for (int c = 0; c < 64; ++c)
        dot = dot + (double)h1p[p][c] * (double)h1p[q][c];
      double d2 = (sqs[p] + sqs[q]) - 2.0 * dot;
      u.s.keys[p][q] = dkey(d2);
    }
  }
  __syncthreads();

  if (t < 32) topk8(&u.s.keys[t][0], &nbr[t][0]);
  __syncthreads();

  float accD[32];
  float embv[32];
  {
    float accA[32];
#pragma unroll
    for (int p = 0; p < 32; ++p) { accA[p] = 0.f; accD[p] = 0.f; }
    for (int c = 0; c < 64; ++c) {
      float wt = w_e2[c * 256 + t];
      float wb = w_e2[(c + 64) * 256 + t];
      float wd = wb - wt;
      const float4* row = (const float4*)&h1t[c][0];
#pragma unroll
      for (int p4 = 0; p4 < 8; ++p4) {
        float4 hv = row[p4];
        accA[4 * p4 + 0] = fmaf(hv.x, wt, accA[4 * p4 + 0]);
        accA[4 * p4 + 1] = fmaf(hv.y, wt, accA[4 * p4 + 1]);
        accA[4 * p4 + 2] = fmaf(hv.z, wt, accA[4 * p4 + 2]);
        accA[4 * p4 + 3] = fmaf(hv.w, wt, accA[4 * p4 + 3]);
        accD[4 * p4 + 0] = fmaf(hv.x, wd, accD[4 * p4 + 0]);
        accD[4 * p4 + 1] = fmaf(hv.y, wd, accD[4 * p4 + 1]);
        accD[4 * p4 + 2] = fmaf(hv.z, wd, accD[4 * p4 + 2]);
        accD[4 * p4 + 3] = fmaf(hv.w, wd, accD[4 * p4 + 3]);
      }
    }
#pragma unroll
    for (int p = 0; p < 32; ++p) u.a2[p * 256 + t] = accA[p];
  }
  __syncthreads();
  {
    float g2v = g2[t], b2v = b2[t];
#pragma unroll
    for (int p = 0; p < 32; ++p) {
      float cd = accD[p];
      float e = -1e30f;
#pragma unroll
      for (int k = 0; k < 8; ++k) {
        int j = nbr[p][k];
        float hv = fmaf(g2v, u.a2[j * 256 + t] + cd, b2v);
        hv = fmaxf(hv, 0.f);
        e = fmaxf(e, hv);
      }
      embv[p] = e;
    }
  }

#pragma unroll
  for (int p = 0; p < 32; ++p) {
    float v = embv[p];
#pragma unroll
    for (int off = 32; off > 0; off >>= 1) v = fmaxf(v, __shfl_xor(v, off));
    if ((t & 63) == 0) part[t >> 6][p] = v;
  }
  __syncthreads();

  if (t < 32) {
    float x1 = fmaxf(fmaxf(part[0][t], part[1][t]), fmaxf(part[2][t], part[3][t]));
    float mx = x1;
#pragma unroll
    for (int off = 16; off > 0; off >>= 1) mx = fmaxf(mx, __shfl_xor(mx, off));
    float ex = expf(x1 - mx);
    float sm = ex;
#pragma unroll
    for (int off = 16; off > 0; off >>= 1) sm += __shfl_xor(sm, off);
    float aw = ex / sm;
    aws[t] = aw;
#pragma unroll
    for (int c = 0; c < 3; ++c) {
      float kv = aw * cl[t][4 + c];
#pragma unroll
      for (int off = 16; off > 0; off >>= 1) kv += __shfl_xor(kv, off);
      if (t == 0) out[((size_t)(b * 3 + c)) * 512 + m] = kv;
    }
  }
  __syncthreads();

  {
    float gsum = 0.f;
    size_t abase = (size_t)O_AFM + (((size_t)(b * 256 + t)) * 512 + m) * 32;
    float4* ap = (float4*)(out + abase);
#pragma unroll
    for (int p4 = 0; p4 < 8; ++p4) {
      float4 o;
      o.x = embv[4 * p4 + 0] * aws[4 * p4 + 0];
      o.y = embv[4 * p4 + 1] * aws[4 * p4 + 1];
      o.z = embv[4 * p4 + 2] * aws[4 * p4 + 2];
      o.w = embv[4 * p4 + 3] * aws[4 * p4 + 3];
      gsum += o.x; gsum += o.y; gsum += o.z; gsum += o.w;
      ap[p4] = o;
    }
    gcf[((size_t)(b * 256 + t)) * 512 + m] = gsum;
  }
}

// ---------------- kernel 4: MLP head ----------------
__global__ __launch_bounds__(256) void mlp_kernel(
    const float* __restrict__ gcf, const float* __restrict__ w_m1,
    const float* __restrict__ bm1, const float* __restrict__ gm1,
    const float* __restrict__ bbm1, const float* __restrict__ w_m2,
    const float* __restrict__ bm2, const float* __restrict__ gm2,
    const float* __restrict__ bbm2, const float* __restrict__ w_m3,
    const float* __restrict__ bm3, float* __restrict__ out) {
  const int blk = blockIdx.x;
  const int b = blk >> 4;
  const int m0 = (blk & 15) << 5;
  const int t = threadIdx.x;
  __shared__ float sbuf[256 * 36];

#pragma unroll
  for (int i = 0; i < 32; ++i) {
    int c = (t >> 5) + (i << 3);
    int j = t & 31;
    sbuf[c * 36 + j] = gcf[((size_t)(b * 256 + c)) * 512 + m0 + j];
  }
  __syncthreads();

  float acc[32];
#pragma unroll
  for (int j = 0; j < 32; ++j) acc[j] = 0.f;
  for (int c = 0; c < 256; ++c) {
    float wv = w_m1[c * 256 + t];
    const float4* row = (const float4*)&sbuf[c * 36];
#pragma unroll
    for (int j4 = 0; j4 < 8; ++j4) {
      float4 g4 = row[j4];
      acc[4 * j4 + 0] = fmaf(g4.x, wv, acc[4 * j4 + 0]);
      acc[4 * j4 + 1] = fmaf(g4.y, wv, acc[4 * j4 + 1]);
      acc[4 * j4 + 2] = fmaf(g4.z, wv, acc[4 * j4 + 2]);
      acc[4 * j4 + 3] = fmaf(g4.w, wv, acc[4 * j4 + 3]);
    }
  }
  float y[32];
  {
    float gv = gm1[t], bv = bm1[t], bbv = bbm1[t];
#pragma unroll
    for (int j = 0; j < 32; ++j) y[j] = fmaxf(fmaf(gv, acc[j] + bv, bbv), 0.f);
  }
  __syncthreads();
#pragma unroll
  for (int j = 0; j < 32; ++j) sbuf[t * 36 + j] = y[j];
  __syncthreads();

#pragma unroll
  for (int j = 0; j < 32; ++j) acc[j] = 0.f;
  for (int c = 0; c < 256; ++c) {
    float wv = w_m2[c * 256 + t];
    const float4* row = (const float4*)&sbuf[c * 36];
#pragma unroll
    for (int j4 = 0; j4 < 8; ++j4) {
      float4 g4 = row[j4];
      acc[4 * j4 + 0] = fmaf(g4.x, wv, acc[4 * j4 + 0]);
      acc[4 * j4 + 1] = fmaf(g4.y, wv, acc[4 * j4 + 1]);
      acc[4 * j4 + 2] = fmaf(g4.z, wv, acc[4 * j4 + 2]);
      acc[4 * j4 + 3] = fmaf(g4.w, wv, acc[4 * j4 + 3]);
    }
  }
  {
    float gv = gm2[t], bv = bm2[t], bbv = bbm2[t];
#pragma unroll
    for (int j = 0; j < 32; ++j) y[j] = fmaxf(fmaf(gv, acc[j] + bv, bbv), 0.f);
  }
  __syncthreads();
  {
    float w3v = w_m3[t];
#pragma unroll
    for (int j = 0; j < 32; ++j) sbuf[t * 36 + j] = y[j] * w3v;
  }
  __syncthreads();
  if (t < 32) {
    float s = 0.f;
    for (int d = 0; d < 256; ++d) s += sbuf[d * 36 + t];
    s += bm3[0];
    float sal = log1pf(expf(-fabsf(s))) + fmaxf(s, 0.f) + 0.001f;
    out[O_SAL + (size_t)b * 512 + m0 + t] = sal;
  }
}

extern "C" void kernel_launch(void* const* d_in, const int* in_sizes, int n_in,
                              void* d_out, int out_size, void* d_ws, size_t ws_size,
                              hipStream_t stream) {
  (void)in_sizes; (void)n_in; (void)out_size; (void)ws_size;
  const float* x = (const float*)d_in[0];
  const int* rand_idx = (const int*)d_in[1];
  const float* w_e1 = (const float*)d_in[2];
  const float* g1 = (const float*)d_in[3];
  const float* b1 = (const float*)d_in[4];
  const float* w_e2 = (const float*)d_in[5];
  const float* g2 = (const float*)d_in[6];
  const float* b2 = (const float*)d_in[7];
  const float* w_m1 = (const float*)d_in[8];
  const float* bm1 = (const float*)d_in[9];
  const float* gm1 = (const float*)d_in[10];
  const float* bbm1 = (const float*)d_in[11];
  const float* w_m2 = (const float*)d_in[12];
  const float* bm2 = (const float*)d_in[13];
  const float* gm2 = (const float*)d_in[14];
  const float* bbm2 = (const float*)d_in[15];
  const float* w_m3 = (const float*)d_in[16];
  const float* bm3 = (const float*)d_in[17];
  float* out = (float*)d_out;
  char* ws = (char*)d_ws;

  float* node = (float*)ws;                             // 32 KB
  float* sqp = (float*)(ws + 32768);                    // 256 KB
  int* sel = (int*)(ws + 32768 + 262144);               // 256 KB
  float* gcf = (float*)(ws + 32768 + 262144 + 262144);  // 2 MB

  sq_kernel<<<256, 256, 0, stream>>>(x, sqp);
  fps_kernel<<<Bn, 1024, 0, stream>>>(x, node);
  knn_kernel<<<Bn * Mn, 256, 0, stream>>>(x, node, sqp, rand_idx, sel);
  group_kernel<<<Bn * Mn, 256, 0, stream>>>(x, node, sel, w_e1, g1, b1, w_e2,
                                            g2, b2, out, gcf);
  mlp_kernel<<<64, 256, 0, stream>>>(gcf, w_m1, bm1, gm1, bbm1, w_m2, bm2, gm2,
                                     bbm2, w_m3, bm3, out);
}

// Round 11
// 1552.731 us; speedup vs baseline: 1.1197x; 1.0760x over previous
//
#include <hip/hip_runtime.h>
#include <cstdint>

#define Bn 4
#define Nn 16384
#define Mn 512
#define Kn 32

// output offsets (floats)
#define O_SAL 6144
#define O_RC  8192
#define O_AFM 794624

__device__ __forceinline__ unsigned fkey(float f) {
  unsigned b = __float_as_uint(f);
  return (b & 0x80000000u) ? ~b : (b | 0x80000000u);
}

__device__ __forceinline__ unsigned long long dkey(double d) {
  unsigned long long b = (unsigned long long)__double_as_longlong(d);
  return (b & 0x8000000000000000ull) ? ~b : (b | 0x8000000000000000ull);
}

// ---- kernel 0: per-point squared norm (np: materialized square + seq sum, NO FMA) ----
__global__ __launch_bounds__(256) void sq_kernel(const float* __restrict__ x,
                                                 float* __restrict__ sqp) {
#pragma clang fp contract(off)
  int i = blockIdx.x * 256 + threadIdx.x;  // < B*N
  float4 v = ((const float4*)x)[i];
  float qx = v.x * v.x;
  float qy = v.y * v.y;
  float qz = v.z * v.z;
  sqp[i] = (qx + qy) + qz;
}

// DPP max step: moved = lane-shuffled v (old = self fallback), then max.
// Values are >= 0 here, so either bound_ctrl semantic (old or 0) is safe.
template <int CTRL>
__device__ __forceinline__ float dppmaxf(float v) {
  int m = __builtin_amdgcn_update_dpp(__float_as_int(v), __float_as_int(v),
                                      CTRL, 0xf, 0xf, false);
  return fmaxf(v, __int_as_float(m));
}

// ---------------- kernel 1: farthest point sampling (fp32, NO contraction) ----------------
// EXACT round-5 version - the best measured fps (887-888us across r5/r9).
// Every structural alternative (multiblock+atomics r7 969, LDS-resident r8
// 985, packed-math r3 894) measured worse. Banked.
__global__ __launch_bounds__(1024)
__attribute__((amdgpu_waves_per_eu(4, 4)))
void fps_kernel(const float* __restrict__ x, float* __restrict__ node) {
#pragma clang fp contract(off)
  const int b = blockIdx.x;
  const int t = threadIdx.x;
  const float4* xb = (const float4*)(x + (size_t)b * Nn * 4);
  float px[16], py[16], pz[16], mind[16];
  const int base = t * 16;
#pragma unroll
  for (int i = 0; i < 16; ++i) {
    float4 v = xb[base + i];
    px[i] = v.x; py[i] = v.y; pz[i] = v.z;
    mind[i] = 1e10f;
  }
  __shared__ __align__(16) unsigned long long kkey[2][16];
  float cx, cy, cz;
  {
    float4 v = xb[0];
    cx = v.x; cy = v.y; cz = v.z;
    if (t == 0) ((float4*)node)[b * Mn] = v;
  }
  for (int s = 1; s < Mn; ++s) {
    // pass 1: distance + running min (exact np order, no contraction)
#pragma unroll
    for (int i = 0; i < 16; ++i) {
      float dx = px[i] - cx;
      float dy = py[i] - cy;
      float dz = pz[i] - cz;
      float qx = dx * dx;
      float qy = dy * dy;
      float qz = dz * dz;
      float d = (qx + qy) + qz;
      mind[i] = fminf(mind[i], d);
    }
    // pass 2: value max tree (v_max returns an input exactly; no NaN here)
    float a0 = fmaxf(mind[0], mind[1]);
    float a1 = fmaxf(mind[2], mind[3]);
    float a2 = fmaxf(mind[4], mind[5]);
    float a3 = fmaxf(mind[6], mind[7]);
    float a4 = fmaxf(mind[8], mind[9]);
    float a5 = fmaxf(mind[10], mind[11]);
    float a6 = fmaxf(mind[12], mind[13]);
    float a7 = fmaxf(mind[14], mind[15]);
    float b0 = fmaxf(a0, a1);
    float b1 = fmaxf(a2, a3);
    float b2 = fmaxf(a4, a5);
    float b3 = fmaxf(a6, a7);
    float bv = fmaxf(fmaxf(b0, b1), fmaxf(b2, b3));
    // pass 3: lowest matching lane-local index (descending scan)
    int isel = 0;
#pragma unroll
    for (int i = 15; i >= 0; --i)
      if (mind[i] == bv) isel = i;
    // wave reduce: value-only DPP max -> lane 63 -> uniform
    float r = bv;
    r = dppmaxf<0x111>(r);  // row_shr:1
    r = dppmaxf<0x112>(r);  // row_shr:2
    r = dppmaxf<0x114>(r);  // row_shr:4
    r = dppmaxf<0x118>(r);  // row_shr:8
    r = dppmaxf<0x142>(r);  // row_bcast:15
    r = dppmaxf<0x143>(r);  // row_bcast:31
    float wmax = __int_as_float(__builtin_amdgcn_readlane(__float_as_int(r), 63));
    unsigned long long ball = __ballot(bv == wmax);
    int wl = __ffsll(ball) - 1;            // lowest tying lane
    int widx = __builtin_amdgcn_readlane(base + isel, wl);
    if ((t & 63) == 0) {
      kkey[s & 1][t >> 6] =
          ((unsigned long long)(__float_as_uint(wmax) | 0x80000000u) << 32) |
          (unsigned)(~widx);
    }
    __syncthreads();
    {
      // lane-parallel block max: lane reads kkey[t&15] (16 u64 = all 32
      // banks; lanes 16+ broadcast), 4-step xor-net max within 16-lane groups
      unsigned long long kk = kkey[s & 1][t & 15];
#pragma unroll
      for (int off = 1; off < 16; off <<= 1) {
        unsigned long long ok = __shfl_xor(kk, off, 16);
        kk = ok > kk ? ok : kk;
      }
      // uniform across the block -> scalarize the winner reload
      int wi = __builtin_amdgcn_readfirstlane((int)(~(unsigned)(kk & 0xFFFFFFFFu)));
      float4 nv = xb[wi];
      cx = nv.x; cy = nv.y; cz = nv.z;
      if (t == 0) ((float4*)node)[b * Mn + s] = nv;
    }
  }
}

// ------- kernel 2: top-64 kNN. EXACT round-5 version (best total, 1623us).
// sq terms NON-FMA; dot = sequential forward FMA; combine unfused. Stable
// lowest-index ties. Byte-wise radix: 4 passes x 256 bins. -------
__global__ __launch_bounds__(256) void knn_kernel(const float* __restrict__ x,
                                                  const float* __restrict__ node,
                                                  const float* __restrict__ sqp,
                                                  const int* __restrict__ rand_idx,
                                                  int* __restrict__ sel) {
#pragma clang fp contract(off)
  const int bm = blockIdx.x;
  const int b = bm >> 9;
  const int t = threadIdx.x;
  const float4* xb = (const float4*)(x + (size_t)b * Nn * 4);
  const float* sq_b = sqp + b * Nn;
  float4 nd = ((const float4*)node)[bm];
  const float nx = nd.x, ny = nd.y, nz = nd.z;
  const float sqmf = (nx * nx + ny * ny) + nz * nz;
  unsigned key[64];
#pragma unroll
  for (int i = 0; i < 64; ++i) {
    int n = t + (i << 8);
    float4 v = xb[n];
    float dot = nx * v.x;
    dot = __builtin_fmaf(ny, v.y, dot);
    dot = __builtin_fmaf(nz, v.z, dot);
    float d2 = (sqmf + sq_b[n]) - 2.0f * dot;
    key[i] = fkey(d2);
  }
  // radix-select the rank-95 (0-indexed) key -> guard-banded superset
  __shared__ unsigned hist[256];
  __shared__ unsigned gsum[16];
  __shared__ unsigned sh_prefix;
  __shared__ int sh_r;
  unsigned prefix = 0, pmask = 0;
  int r = 95;
  for (int shift = 24; shift >= 0; shift -= 8) {
    hist[t] = 0;
    __syncthreads();
#pragma unroll
    for (int i = 0; i < 64; ++i) {
      if ((key[i] & pmask) == prefix) atomicAdd(&hist[(key[i] >> shift) & 255], 1u);
    }
    __syncthreads();
    if (t < 16) {
      unsigned ssum = 0;
#pragma unroll
      for (int j = 0; j < 16; ++j) ssum += hist[t * 16 + j];
      gsum[t] = ssum;
    }
    __syncthreads();
    if (t == 0) {
      int rr = r;
      unsigned g = 0;
      for (unsigned j = 0; j < 16; ++j) {
        int c = (int)gsum[j];
        if (rr < c) { g = j; break; }
        rr -= c;
      }
      unsigned bin = g * 16;
      for (unsigned j = 0; j < 16; ++j) {
        int c = (int)hist[g * 16 + j];
        if (rr < c) { bin = g * 16 + j; break; }
        rr -= c;
      }
      sh_prefix = prefix | (bin << shift);
      sh_r = rr;
    }
    __syncthreads();
    prefix = sh_prefix;
    r = sh_r;
    pmask |= (0xFFu << shift);
  }
  const unsigned T = prefix;  // collect all keys <= T (>=96 candidates; cap 128)
  __shared__ int cnt;
  __shared__ unsigned long long karr[128];
  if (t == 0) cnt = 0;
  __syncthreads();
#pragma unroll
  for (int i = 0; i < 64; ++i) {
    if (key[i] <= T) {
      int pos = atomicAdd(&cnt, 1);
      if (pos < 128) {
        unsigned n = (unsigned)(t + (i << 8));
        // idx in low bits: ascending sort => equal d2 resolved LOWEST index first
        karr[pos] = ((unsigned long long)key[i] << 32) | n;
      }
    }
  }
  __syncthreads();
  const int nc = cnt < 128 ? cnt : 128;
  if (t < 128 && t >= nc) karr[t] = ~0ull;
  // 128-wide bitonic sort ascending
  for (int k = 2; k <= 128; k <<= 1) {
    for (int j = k >> 1; j > 0; j >>= 1) {
      __syncthreads();
      if (t < 64) {
        int i = ((t & ~(j - 1)) << 1) | (t & (j - 1));
        int ip = i | j;
        unsigned long long ka = karr[i], kb = karr[ip];
        bool asc = ((i & k) == 0);
        if ((ka > kb) == asc) { karr[i] = kb; karr[ip] = ka; }
      }
    }
  }
  __syncthreads();
  if (t < 32) {
    int ri = rand_idx[t];  // in [0,64)
    sel[bm * 32 + t] = (int)(unsigned)(karr[ri] & 0xFFFFFFFFu);
  }
}

// ---------------- kernel 3: fused group pipeline ----------------
// RESUBMISSION of r10 (container failed with no diagnostics; diff audit
// found no crash mechanism: rank-select is all-LDS, bounds-checked (r<8),
// barrier-covered, no new global memory/atomics/launch change - unlike r6's
// failure which had a concrete OOB-atomic mechanism. Infra flakiness is the
// leading explanation; a second failure on identical source would implicate
// the kernel and trigger a revert).
// Change vs r9: the two serial topk8 phases (32 threads, 32-iter insertion
// sort, dependent ~120cy LDS loads, 224 threads idle) are replaced by an
// all-256-thread PARALLEL RANK-SELECT: rank(q) = #{j: key[j]<key[q]} +
// #{j<q: key[j]==key[q]} - provably the same stable lowest-index-ties order;
// ranks 0..31 are a permutation, so nbr[p][rank<8]=q writes exactly the same
// top-8 set in the same order. Reads lane-staggered (jj=(j+p)&31) ->
// conflict-free. Also: 64-d fp64 pairwise dot float4-vectorized + unrolled
// (same sequential accumulation order -> bit-identical).
__global__ __launch_bounds__(256) void group_kernel(
    const float* __restrict__ x, const float* __restrict__ node,
    const int* __restrict__ sel, const float* __restrict__ w_e1,
    const float* __restrict__ g1, const float* __restrict__ b1,
    const float* __restrict__ w_e2, const float* __restrict__ g2,
    const float* __restrict__ b2, float* __restrict__ out,
    float* __restrict__ gcf) {
#pragma clang fp contract(off)
  const int bm = blockIdx.x;
  const int b = bm >> 9;
  const int m = bm & 511;
  const int t = threadIdx.x;

  __shared__ float cl[32][13];
  __shared__ float h1t[64][36];
  __shared__ float h1p[32][68];
  __shared__ unsigned char nbr[32][8];
  __shared__ double sqs[32];
  __shared__ float part[4][32];
  __shared__ float aws[32];
  __shared__ union U {
    struct {
      unsigned long long keys[32][32];
      float we_a[12][64];
      float we_d[12][64];
      float a1[32][65];
      float cd1[32][65];
    } s;
    float a2[32 * 256];
  } u;

  const float4* xb = (const float4*)(x + (size_t)b * Nn * 4);
  const float4 ndv = ((const float4*)node)[bm];

  if (t < 32) {
    int n = sel[bm * 32 + t];
    float4 v = xb[n];
    float rx = v.x - ndv.x;
    float ry = v.y - ndv.y;
    float rz = v.z - ndv.z;
    float ds = (rx * rx + ry * ry) + rz * rz;
    ds = __fsqrt_rn(ds);
    cl[t][0] = ndv.x; cl[t][1] = ndv.y; cl[t][2] = ndv.z; cl[t][3] = ndv.w;
    cl[t][4] = v.x;   cl[t][5] = v.y;   cl[t][6] = v.z;   cl[t][7] = v.w;
    cl[t][8] = rx;    cl[t][9] = ry;    cl[t][10] = rz;   cl[t][11] = ds;
  }
  for (int i = t; i < 768; i += 256) {
    int row = i >> 6, d = i & 63;
    float wa = w_e1[row * 64 + d];
    float wb = w_e1[(row + 12) * 64 + d];
    u.s.we_a[row][d] = wa;
    u.s.we_d[row][d] = wb - wa;
  }
  __syncthreads();

  for (int i = t; i < 384; i += 256) {
    int c = i >> 5, p = i & 31;
    out[O_RC + (((size_t)(b * 12 + c) * 512) + m) * 32 + p] = cl[p][c];
  }
  if (t < 32) {
    double q[12];
#pragma unroll
    for (int c = 0; c < 12; ++c) {
      double cv = (double)cl[t][c];
      q[c] = cv * cv;
    }
    double s01 = q[0] + q[1];
    double s23 = q[2] + q[3];
    double s45 = q[4] + q[5];
    double s67 = q[6] + q[7];
    double s = (s01 + s23) + (s45 + s67);
    s = s + q[8];
    s = s + q[9];
    s = s + q[10];
    s = s + q[11];
    sqs[t] = s;
  }
  __syncthreads();

  // pairwise d2 (12-d, fp64 order-exact) -> keys
  {
    int p = t >> 3, q0 = (t & 7) << 2;
#pragma unroll
    for (int qq = 0; qq < 4; ++qq) {
      int q = q0 + qq;
      double dot = 0.0;
#pragma unroll
      for (int c = 0; c < 12; ++c)
        dot = dot + (double)cl[p][c] * (double)cl[q][c];
      double d2 = (sqs[p] + sqs[q]) - 2.0 * dot;
      u.s.keys[p][q] = dkey(d2);
    }
  }
  __syncthreads();

  // parallel rank-select top-8 (replaces serial topk8; identical semantics)
  {
    int p = t >> 3, s8 = t & 7;
    unsigned long long kq0 = u.s.keys[p][s8];
    unsigned long long kq1 = u.s.keys[p][s8 + 8];
    unsigned long long kq2 = u.s.keys[p][s8 + 16];
    unsigned long long kq3 = u.s.keys[p][s8 + 24];
    int r0 = 0, r1 = 0, r2 = 0, r3 = 0;
#pragma unroll
    for (int j = 0; j < 32; ++j) {
      int jj = (j + p) & 31;  // lane-staggered: conflict-free row reads
      unsigned long long kj = u.s.keys[p][jj];
      r0 += (kj < kq0 || (kj == kq0 && jj < s8));
      r1 += (kj < kq1 || (kj == kq1 && jj < s8 + 8));
      r2 += (kj < kq2 || (kj == kq2 && jj < s8 + 16));
      r3 += (kj < kq3 || (kj == kq3 && jj < s8 + 24));
    }
    if (r0 < 8) nbr[p][r0] = (unsigned char)s8;
    if (r1 < 8) nbr[p][r1] = (unsigned char)(s8 + 8);
    if (r2 < 8) nbr[p][r2] = (unsigned char)(s8 + 16);
    if (r3 < 8) nbr[p][r3] = (unsigned char)(s8 + 24);
  }
  {
    int d = t & 63, pg = (t >> 6) << 3;
#pragma unroll
    for (int pp = 0; pp < 8; ++pp) {
      int p = pg + pp;
      float aA = 0.f, aD = 0.f;
#pragma unroll
      for (int c = 0; c < 12; ++c) {
        float xv = cl[p][c];
        aA = fmaf(xv, u.s.we_a[c][d], aA);
        aD = fmaf(xv, u.s.we_d[c][d], aD);
      }
      u.s.a1[p][d] = aA;
      u.s.cd1[p][d] = aD;
    }
  }
  __syncthreads();

  {
    int d = t & 63, pg = (t >> 6) << 3;
    float g1v = g1[d], b1v = b1[d];
#pragma unroll
    for (int pp = 0; pp < 8; ++pp) {
      int p = pg + pp;
      float cd = u.s.cd1[p][d];
      float hm = -1e30f;
#pragma unroll
      for (int k = 0; k < 8; ++k) {
        int j = nbr[p][k];
        float hv = fmaf(g1v, u.s.a1[j][d] + cd, b1v);
        hv = fmaxf(hv, 0.f);
        hm = fmaxf(hm, hv);
      }
      h1t[d][p] = hm;
      h1p[p][d] = hm;
    }
  }
  __syncthreads();

  if (t < 32) {
    double r[8];
#pragma unroll
    for (int j = 0; j < 8; ++j) {
      double hv = (double)h1p[t][j];
      r[j] = hv * hv;
    }
#pragma unroll
    for (int blk = 1; blk < 8; ++blk) {
#pragma unroll
      for (int j = 0; j < 8; ++j) {
        double hv = (double)h1p[t][blk * 8 + j];
        r[j] = r[j] + hv * hv;
      }
    }
    double s01 = r[0] + r[1];
    double s23 = r[2] + r[3];
    double s45 = r[4] + r[5];
    double s67 = r[6] + r[7];
    sqs[t] = (s01 + s23) + (s45 + s67);
  }
  __syncthreads();

  // pairwise d2 over h1 (64-d, fp64, float4-vectorized; same seq order)
  {
    int p = t >> 3, q0 = (t & 7) << 2;
    const float4* rp = (const float4*)&h1p[p][0];
    for (int qq = 0; qq < 4; ++qq) {
      int q = q0 + qq;
      const float4* rq = (const float4*)&h1p[q][0];
      double dot = 0.0;
#pragma unroll
      for (int c4 = 0; c4 < 16; ++c4) {
        float4 av = rp[c4];
        float4 bv = rq[c4];
        dot = dot + (double)av.x * (double)bv.x;
        dot = dot + (double)av.y * (double)bv.y;
        dot = dot + (double)av.z * (double)bv.z;
        dot = dot + (double)av.w * (double)bv.w;
      }
      double d2 = (sqs[p] + sqs[q]) - 2.0 * dot;
      u.s.keys[p][q] = dkey(d2);
    }
  }
  __syncthreads();

  // parallel rank-select top-8 (second neighbor search)
  {
    int p = t >> 3, s8 = t & 7;
    unsigned long long kq0 = u.s.keys[p][s8];
    unsigned long long kq1 = u.s.keys[p][s8 + 8];
    unsigned long long kq2 = u.s.keys[p][s8 + 16];
    unsigned long long kq3 = u.s.keys[p][s8 + 24];
    int r0 = 0, r1 = 0, r2 = 0, r3 = 0;
#pragma unroll
    for (int j = 0; j < 32; ++j) {
      int jj = (j + p) & 31;
      unsigned long long kj = u.s.keys[p][jj];
      r0 += (kj < kq0 || (kj == kq0 && jj < s8));
      r1 += (kj < kq1 || (kj == kq1 && jj < s8 + 8));
      r2 += (kj < kq2 || (kj == kq2 && jj < s8 + 16));
      r3 += (kj < kq3 || (kj == kq3 && jj < s8 + 24));
    }
    if (r0 < 8) nbr[p][r0] = (unsigned char)s8;
    if (r1 < 8) nbr[p][r1] = (unsigned char)(s8 + 8);
    if (r2 < 8) nbr[p][r2] = (unsigned char)(s8 + 16);
    if (r3 < 8) nbr[p][r3] = (unsigned char)(s8 + 24);
  }
  __syncthreads();

  float accD[32];
  float embv[32];
  {
    float accA[32];
#pragma unroll
    for (int p = 0; p < 32; ++p) { accA[p] = 0.f; accD[p] = 0.f; }
    for (int c = 0; c < 64; ++c) {
      float wt = w_e2[c * 256 + t];
      float wb = w_e2[(c + 64) * 256 + t];
      float wd = wb - wt;
      const float4* row = (const float4*)&h1t[c][0];
#pragma unroll
      for (int p4 = 0; p4 < 8; ++p4) {
        float4 hv = row[p4];
        accA[4 * p4 + 0] = fmaf(hv.x, wt, accA[4 * p4 + 0]);
        accA[4 * p4 + 1] = fmaf(hv.y, wt, accA[4 * p4 + 1]);
        accA[4 * p4 + 2] = fmaf(hv.z, wt, accA[4 * p4 + 2]);
        accA[4 * p4 + 3] = fmaf(hv.w, wt, accA[4 * p4 + 3]);
        accD[4 * p4 + 0] = fmaf(hv.x, wd, accD[4 * p4 + 0]);
        accD[4 * p4 + 1] = fmaf(hv.y, wd, accD[4 * p4 + 1]);
        accD[4 * p4 + 2] = fmaf(hv.z, wd, accD[4 * p4 + 2]);
        accD[4 * p4 + 3] = fmaf(hv.w, wd, accD[4 * p4 + 3]);
      }
    }
#pragma unroll
    for (int p = 0; p < 32; ++p) u.a2[p * 256 + t] = accA[p];
  }
  __syncthreads();
  {
    float g2v = g2[t], b2v = b2[t];
#pragma unroll
    for (int p = 0; p < 32; ++p) {
      float cd = accD[p];
      float e = -1e30f;
#pragma unroll
      for (int k = 0; k < 8; ++k) {
        int j = nbr[p][k];
        float hv = fmaf(g2v, u.a2[j * 256 + t] + cd, b2v);
        hv = fmaxf(hv, 0.f);
        e = fmaxf(e, hv);
      }
      embv[p] = e;
    }
  }

#pragma unroll
  for (int p = 0; p < 32; ++p) {
    float v = embv[p];
#pragma unroll
    for (int off = 32; off > 0; off >>= 1) v = fmaxf(v, __shfl_xor(v, off));
    if ((t & 63) == 0) part[t >> 6][p] = v;
  }
  __syncthreads();

  if (t < 32) {
    float x1 = fmaxf(fmaxf(part[0][t], part[1][t]), fmaxf(part[2][t], part[3][t]));
    float mx = x1;
#pragma unroll
    for (int off = 16; off > 0; off >>= 1) mx = fmaxf(mx, __shfl_xor(mx, off));
    float ex = expf(x1 - mx);
    float sm = ex;
#pragma unroll
    for (int off = 16; off > 0; off >>= 1) sm += __shfl_xor(sm, off);
    float aw = ex / sm;
    aws[t] = aw;
#pragma unroll
    for (int c = 0; c < 3; ++c) {
      float kv = aw * cl[t][4 + c];
#pragma unroll
      for (int off = 16; off > 0; off >>= 1) kv += __shfl_xor(kv, off);
      if (t == 0) out[((size_t)(b * 3 + c)) * 512 + m] = kv;
    }
  }
  __syncthreads();

  {
    float gsum = 0.f;
    size_t abase = (size_t)O_AFM + (((size_t)(b * 256 + t)) * 512 + m) * 32;
    float4* ap = (float4*)(out + abase);
#pragma unroll
    for (int p4 = 0; p4 < 8; ++p4) {
      float4 o;
      o.x = embv[4 * p4 + 0] * aws[4 * p4 + 0];
      o.y = embv[4 * p4 + 1] * aws[4 * p4 + 1];
      o.z = embv[4 * p4 + 2] * aws[4 * p4 + 2];
      o.w = embv[4 * p4 + 3] * aws[4 * p4 + 3];
      gsum += o.x; gsum += o.y; gsum += o.z; gsum += o.w;
      ap[p4] = o;
    }
    gcf[((size_t)(b * 256 + t)) * 512 + m] = gsum;
  }
}

// ---------------- kernel 4: MLP head ----------------
__global__ __launch_bounds__(256) void mlp_kernel(
    const float* __restrict__ gcf, const float* __restrict__ w_m1,
    const float* __restrict__ bm1, const float* __restrict__ gm1,
    const float* __restrict__ bbm1, const float* __restrict__ w_m2,
    const float* __restrict__ bm2, const float* __restrict__ gm2,
    const float* __restrict__ bbm2, const float* __restrict__ w_m3,
    const float* __restrict__ bm3, float* __restrict__ out) {
  const int blk = blockIdx.x;
  const int b = blk >> 4;
  const int m0 = (blk & 15) << 5;
  const int t = threadIdx.x;
  __shared__ float sbuf[256 * 36];

#pragma unroll
  for (int i = 0; i < 32; ++i) {
    int c = (t >> 5) + (i << 3);
    int j = t & 31;
    sbuf[c * 36 + j] = gcf[((size_t)(b * 256 + c)) * 512 + m0 + j];
  }
  __syncthreads();

  float acc[32];
#pragma unroll
  for (int j = 0; j < 32; ++j) acc[j] = 0.f;
  for (int c = 0; c < 256; ++c) {
    float wv = w_m1[c * 256 + t];
    const float4* row = (const float4*)&sbuf[c * 36];
#pragma unroll
    for (int j4 = 0; j4 < 8; ++j4) {
      float4 g4 = row[j4];
      acc[4 * j4 + 0] = fmaf(g4.x, wv, acc[4 * j4 + 0]);
      acc[4 * j4 + 1] = fmaf(g4.y, wv, acc[4 * j4 + 1]);
      acc[4 * j4 + 2] = fmaf(g4.z, wv, acc[4 * j4 + 2]);
      acc[4 * j4 + 3] = fmaf(g4.w, wv, acc[4 * j4 + 3]);
    }
  }
  float y[32];
  {
    float gv = gm1[t], bv = bm1[t], bbv = bbm1[t];
#pragma unroll
    for (int j = 0; j < 32; ++j) y[j] = fmaxf(fmaf(gv, acc[j] + bv, bbv), 0.f);
  }
  __syncthreads();
#pragma unroll
  for (int j = 0; j < 32; ++j) sbuf[t * 36 + j] = y[j];
  __syncthreads();

#pragma unroll
  for (int j = 0; j < 32; ++j) acc[j] = 0.f;
  for (int c = 0; c < 256; ++c) {
    float wv = w_m2[c * 256 + t];
    const float4* row = (const float4*)&sbuf[c * 36];
#pragma unroll
    for (int j4 = 0; j4 < 8; ++j4) {
      float4 g4 = row[j4];
      acc[4 * j4 + 0] = fmaf(g4.x, wv, acc[4 * j4 + 0]);
      acc[4 * j4 + 1] = fmaf(g4.y, wv, acc[4 * j4 + 1]);
      acc[4 * j4 + 2] = fmaf(g4.z, wv, acc[4 * j4 + 2]);
      acc[4 * j4 + 3] = fmaf(g4.w, wv, acc[4 * j4 + 3]);
    }
  }
  {
    float gv = gm2[t], bv = bm2[t], bbv = bbm2[t];
#pragma unroll
    for (int j = 0; j < 32; ++j) y[j] = fmaxf(fmaf(gv, acc[j] + bv, bbv), 0.f);
  }
  __syncthreads();
  {
    float w3v = w_m3[t];
#pragma unroll
    for (int j = 0; j < 32; ++j) sbuf[t * 36 + j] = y[j] * w3v;
  }
  __syncthreads();
  if (t < 32) {
    float s = 0.f;
    for (int d = 0; d < 256; ++d) s += sbuf[d * 36 + t];
    s += bm3[0];
    float sal = log1pf(expf(-fabsf(s))) + fmaxf(s, 0.f) + 0.001f;
    out[O_SAL + (size_t)b * 512 + m0 + t] = sal;
  }
}

extern "C" void kernel_launch(void* const* d_in, const int* in_sizes, int n_in,
                              void* d_out, int out_size, void* d_ws, size_t ws_size,
                              hipStream_t stream) {
  (void)in_sizes; (void)n_in; (void)out_size; (void)ws_size;
  const float* x = (const float*)d_in[0];
  const int* rand_idx = (const int*)d_in[1];
  const float* w_e1 = (const float*)d_in[2];
  const float* g1 = (const float*)d_in[3];
  const float* b1 = (const float*)d_in[4];
  const float* w_e2 = (const float*)d_in[5];
  const float* g2 = (const float*)d_in[6];
  const float* b2 = (const float*)d_in[7];
  const float* w_m1 = (const float*)d_in[8];
  const float* bm1 = (const float*)d_in[9];
  const float* gm1 = (const float*)d_in[10];
  const float* bbm1 = (const float*)d_in[11];
  const float* w_m2 = (const float*)d_in[12];
  const float* bm2 = (const float*)d_in[13];
  const float* gm2 = (const float*)d_in[14];
  const float* bbm2 = (const float*)d_in[15];
  const float* w_m3 = (const float*)d_in[16];
  const float* bm3 = (const float*)d_in[17];
  float* out = (float*)d_out;
  char* ws = (char*)d_ws;

  float* node = (float*)ws;                             // 32 KB
  float* sqp = (float*)(ws + 32768);                    // 256 KB
  int* sel = (int*)(ws + 32768 + 262144);               // 256 KB
  float* gcf = (float*)(ws + 32768 + 262144 + 262144);  // 2 MB

  sq_kernel<<<256, 256, 0, stream>>>(x, sqp);
  fps_kernel<<<Bn, 1024, 0, stream>>>(x, node);
  knn_kernel<<<Bn * Mn, 256, 0, stream>>>(x, node, sqp, rand_idx, sel);
  group_kernel<<<Bn * Mn, 256, 0, stream>>>(x, node, sel, w_e1, g1, b1, w_e2,
                                            g2, b2, out, gcf);
  mlp_kernel<<<64, 256, 0, stream>>>(gcf, w_m1, bm1, gm1, bbm1, w_m2, bm2, gm2,
                                     bbm2, w_m3, bm3, out);
}